// Round 1
// baseline (9830.022 us; speedup 1.0000x reference)
//
#include <hip/hip_runtime.h>
#include <hip/hip_bf16.h>

// Problem: B=2, S=4096, D=1024, H=16, HD=64, M=512, L=1024, HID=2816, 8 scan steps.
// Key insight: attention output for memory queries (pos<512) is discarded -> only
// compute 512 query rows per step.
// Dtype ambiguity (fp32-per-reference vs bf16-per-harness-evidence) resolved at
// runtime by probing input bit patterns; all converts + final store branch on flag.

#define D_    1024
#define H_    16
#define HD_   64
#define M_    512
#define L_    1024
#define HID_  2816
#define NSTEP 8

typedef __hip_bfloat16 bf16;
typedef __attribute__((ext_vector_type(8))) short short8;
typedef __attribute__((ext_vector_type(4))) float floatx4;

// ---------------- dtype probe ----------------
// x ~ N(0,1). If buffer is bf16, u16[2*l] are sane bf16 (exp field ~[117,129]).
// If buffer is fp32, u16[2*l] are fp32 mantissa-low halves: ~uniform garbage.
__global__ void probe_dtype(const void* x, int* flag) {
  int lane = threadIdx.x;
  unsigned short v = ((const unsigned short*)x)[2 * lane];
  int e = (v >> 7) & 0xFF;
  bool sane = (e >= 100 && e <= 140);
  unsigned long long m = __ballot(sane);
  if (lane == 0) flag[0] = (__popcll(m) >= 40) ? 1 : 0;  // 1 = bf16 inputs
}

__device__ __forceinline__ float load_any(const void* p, long i, int isbf) {
  return isbf ? __bfloat162float(((const bf16*)p)[i]) : ((const float*)p)[i];
}

// ---------------- converts ----------------
// (K x N) row-major -> (N x K) bf16 row-major
__global__ __launch_bounds__(256) void transpose_cast(const void* in, bf16* out,
                                                      int K, int N, const int* flagp) {
  __shared__ float tile[32][33];
  int isbf = flagp[0];
  int tx = threadIdx.x & 31, ty = threadIdx.x >> 5;
  int n = blockIdx.x * 32 + tx;
#pragma unroll
  for (int i = 0; i < 4; i++) {
    int k = blockIdx.y * 32 + ty + i * 8;
    tile[ty + i * 8][tx] = load_any(in, (long)k * N + n, isbf);
  }
  __syncthreads();
  int k2 = blockIdx.y * 32 + tx;
#pragma unroll
  for (int i = 0; i < 4; i++) {
    int n2 = blockIdx.x * 32 + ty + i * 8;
    out[(long)n2 * K + k2] = __float2bfloat16(tile[tx][ty + i * 8]);
  }
}

__global__ __launch_bounds__(256) void cast_to_bf16(const void* in, bf16* out, int n,
                                                    const int* flagp) {
  int i = blockIdx.x * 256 + threadIdx.x;
  if (i < n) out[i] = __float2bfloat16(load_any(in, i, flagp[0]));
}

__global__ __launch_bounds__(256) void cast_to_f32(const void* in, float* out, int n,
                                                   const int* flagp) {
  int i = blockIdx.x * 256 + threadIdx.x;
  if (i < n) out[i] = load_any(in, i, flagp[0]);
}

// origin_mem (1,512,1024) broadcast to om (2*512,1024) bf16
__global__ __launch_bounds__(256) void init_om(const void* in, bf16* om, const int* flagp) {
  int i = blockIdx.x * 256 + threadIdx.x;  // 1048576
  int rem = i & (M_ * D_ - 1);
  om[i] = __float2bfloat16(load_any(in, rem, flagp[0]));
}

// ---------------- MFMA GEMM ----------------
// C(Mrows x N) = A(bf16, mapped rows, row-major K) @ WT(bf16, N x K row-major)^T
// 64x64 block tile, BK=64, 256 threads = 4 waves (2x2), each wave 32x32 via 2x2
// mfma_f32_16x16x32_bf16. LDS chunks XOR-swizzled: chunk(m,c) at (m*8 + (c^(m&7)))*16 B
// -> both ds_write_b128 staging and ds_read_b128 fragment reads are bank-optimal.
// A-frag: A[m=lane&15][k=(lane>>4)*8+j]; B-frag: WT[n=lane&15][k=(lane>>4)*8+j];
// C/D: col=lane&15, row=(lane>>4)*4+reg   [m89/m91-verified layouts]
__global__ __launch_bounds__(256) void gemm_bf16(
    const bf16* __restrict__ A, const bf16* __restrict__ WT, float* __restrict__ Cf,
    void* __restrict__ dout, const int* __restrict__ flagp, int Mrows, int N, int K,
    int row_inner, int row_outer, int row_off, int to_dout) {
  __shared__ char smem[16384];
  char* aT = smem;
  char* bT = smem + 8192;
  int tid = threadIdx.x;
  int C0 = blockIdx.x * 64, R0 = blockIdx.y * 64;
  int wave = tid >> 6, lane = tid & 63;
  int wm_ = wave >> 1, wn_ = wave & 1;
  floatx4 acc[2][2] = {};

  int q0 = tid, q1 = tid + 256;
  int am0 = q0 >> 3, ac0 = q0 & 7;
  int am1 = q1 >> 3, ac1 = q1 & 7;
  int r0 = R0 + am0, r1 = R0 + am1;
  long grow0 = (long)(r0 / row_inner) * row_outer + row_off + (r0 % row_inner);
  long grow1 = (long)(r1 / row_inner) * row_outer + row_off + (r1 % row_inner);
  long bn0 = (long)(C0 + am0) * K, bn1 = (long)(C0 + am1) * K;
  int lofa0 = (am0 * 8 + (ac0 ^ (am0 & 7))) * 16;
  int lofa1 = (am1 * 8 + (ac1 ^ (am1 & 7))) * 16;

  for (int k0 = 0; k0 < K; k0 += 64) {
    uint4 va0 = *(const uint4*)(A + grow0 * K + k0 + ac0 * 8);
    uint4 va1 = *(const uint4*)(A + grow1 * K + k0 + ac1 * 8);
    uint4 vb0 = *(const uint4*)(WT + bn0 + k0 + ac0 * 8);
    uint4 vb1 = *(const uint4*)(WT + bn1 + k0 + ac1 * 8);
    __syncthreads();
    *(uint4*)(aT + lofa0) = va0;
    *(uint4*)(aT + lofa1) = va1;
    *(uint4*)(bT + lofa0) = vb0;
    *(uint4*)(bT + lofa1) = vb1;
    __syncthreads();
#pragma unroll
    for (int kki = 0; kki < 2; ++kki) {
      int cbase = kki * 4 + (lane >> 4);
      short8 af[2], bfr[2];
#pragma unroll
      for (int i = 0; i < 2; ++i) {
        int ml = wm_ * 32 + i * 16 + (lane & 15);
        af[i] = *(const short8*)(aT + (ml * 8 + (cbase ^ (ml & 7))) * 16);
        int nl = wn_ * 32 + i * 16 + (lane & 15);
        bfr[i] = *(const short8*)(bT + (nl * 8 + (cbase ^ (nl & 7))) * 16);
      }
#pragma unroll
      for (int i = 0; i < 2; ++i)
#pragma unroll
        for (int j = 0; j < 2; ++j)
          acc[i][j] = __builtin_amdgcn_mfma_f32_16x16x32_bf16(af[i], bfr[j], acc[i][j], 0, 0, 0);
    }
  }
  int isbf = flagp[0];
#pragma unroll
  for (int i = 0; i < 2; ++i)
#pragma unroll
    for (int j = 0; j < 2; ++j) {
      int row = R0 + wm_ * 32 + i * 16 + (lane >> 4) * 4;
      int col = C0 + wn_ * 32 + j * 16 + (lane & 15);
#pragma unroll
      for (int rg = 0; rg < 4; ++rg) {
        float v = acc[i][j][rg];
        long off = (long)(row + rg) * N + col;
        if (to_dout) {
          if (isbf) ((bf16*)dout)[off] = __float2bfloat16(v);
          else ((float*)dout)[off] = v;
        } else {
          Cf[off] = v;
        }
      }
    }
}

// ---------------- elementwise ----------------
// Y = rmsnorm(X (+ Xadd), Wn) cast to bf16. One block per row of 1024.
__global__ __launch_bounds__(256) void rmsnorm_cast(const float* __restrict__ X,
                                                    const float* __restrict__ Wn,
                                                    bf16* __restrict__ Y,
                                                    const float* __restrict__ Xadd) {
  int row = blockIdx.x, tid = threadIdx.x;
  const float* xr = X + (long)row * D_;
  float vals[4], ss = 0.f;
#pragma unroll
  for (int i = 0; i < 4; i++) {
    int c = tid + i * 256;
    float v = xr[c];
    if (Xadd) v += Xadd[(long)row * D_ + c];
    vals[i] = v;
    ss += v * v;
  }
#pragma unroll
  for (int off = 32; off; off >>= 1) ss += __shfl_xor(ss, off);
  __shared__ float wsum[4];
  int wv = tid >> 6, lane = tid & 63;
  if (lane == 0) wsum[wv] = ss;
  __syncthreads();
  ss = wsum[0] + wsum[1] + wsum[2] + wsum[3];
  float r = rsqrtf(ss * (1.0f / D_) + 1e-5f);
#pragma unroll
  for (int i = 0; i < 4; i++) {
    int c = tid + i * 256;
    Y[(long)row * D_ + c] = __float2bfloat16(vals[i] * r * Wn[c]);
  }
}

// u = silu(g13[:, :2816]) * g13[:, 2816:]  -> bf16
__global__ __launch_bounds__(256) void silu_mul_cast(const float* __restrict__ g13,
                                                     bf16* __restrict__ u) {
  int c = blockIdx.x * 256 + threadIdx.x;  // 0..2815
  int r = blockIdx.y;
  float a = g13[(long)r * (2 * HID_) + c];
  float b = g13[(long)r * (2 * HID_) + HID_ + c];
  float s = a / (1.f + __expf(-a));
  u[(long)r * HID_ + c] = __float2bfloat16(s * b);
}

// Build roped q (x-part only), k, v in (bh, pos, hd) fp32 layout.
// qkvf: (b*512+m, 3072) [q|k|v], mkv: (b*512+m, 2048) [mk|mv]
__global__ __launch_bounds__(256) void rope_build(
    const float* __restrict__ qkvf, const float* __restrict__ mkv,
    const float* __restrict__ cosf, const float* __restrict__ sinf,
    float* __restrict__ qall, float* __restrict__ kall, float* __restrict__ vall) {
  int idx = blockIdx.x * 256 + threadIdx.x;  // 2*16*1024*32 = 1048576
  int i = idx & 31;
  int pos = (idx >> 5) & 1023;
  int bh = idx >> 15;  // 0..31
  int b = bh >> 4, h = bh & 15;
  float c = cosf[pos * 32 + i], s = sinf[pos * 32 + i];
  float k0, k1, v0, v1;
  if (pos < M_) {
    long base = ((long)(b * M_ + pos)) * 2048 + h * HD_ + 2 * i;
    k0 = mkv[base]; k1 = mkv[base + 1];
    v0 = mkv[base + 1024]; v1 = mkv[base + 1025];
  } else {
    long base = ((long)(b * M_ + pos - M_)) * 3072 + 1024 + h * HD_ + 2 * i;
    k0 = qkvf[base]; k1 = qkvf[base + 1];
    v0 = qkvf[base + 1024]; v1 = qkvf[base + 1025];
  }
  long ko = ((long)bh) * (L_ * HD_) + pos * HD_ + 2 * i;
  kall[ko] = k0 * c - k1 * s;
  kall[ko + 1] = k0 * s + k1 * c;
  vall[ko] = v0;
  vall[ko + 1] = v1;
  if (pos >= M_) {
    long qbase = ((long)(b * M_ + pos - M_)) * 3072 + h * HD_ + 2 * i;
    float q0 = qkvf[qbase], q1 = qkvf[qbase + 1];
    long qo = ((long)bh) * (M_ * HD_) + (pos - M_) * HD_ + 2 * i;
    qall[qo] = q0 * c - q1 * s;
    qall[qo + 1] = q0 * s + q1 * c;
  }
}

// Online-softmax attention: 1 wave per x-query row (pos P = 512+q), keys 0..P.
// lane = head dim. att layout: (b*512+q, 1024) matching downstream GEMM A rows.
__global__ __launch_bounds__(256) void attn_kernel(const float* __restrict__ qall,
                                                   const float* __restrict__ kall,
                                                   const float* __restrict__ vall,
                                                   float* __restrict__ att) {
  int bx = blockIdx.x;      // 0..4095
  int bh = bx >> 7;         // 0..31
  int q4 = bx & 127;
  int wave = threadIdx.x >> 6, lane = threadIdx.x & 63;
  int q = q4 * 4 + wave;    // 0..511
  int P = M_ + q;
  float qd = qall[(long)bh * (M_ * HD_) + q * HD_ + lane] * 0.125f;
  const float* kb = kall + (long)bh * (L_ * HD_);
  const float* vb = vall + (long)bh * (L_ * HD_);
  float m = -1e30f, l = 0.f, acc = 0.f;
  for (int t = 0; t <= P; ++t) {
    float s = qd * kb[t * HD_ + lane];
#pragma unroll
    for (int off = 32; off; off >>= 1) s += __shfl_xor(s, off);
    float mn = fmaxf(m, s);
    float pw = __expf(s - mn);
    float corr = __expf(m - mn);
    l = l * corr + pw;
    acc = acc * corr + pw * vb[t * HD_ + lane];
    m = mn;
  }
  int b = bh >> 4, h = bh & 15;
  att[((long)(b * M_ + q)) * D_ + h * HD_ + lane] = acc / l;
}

// om_bf <- bf16(att); outs_bf[b*4096 + t*512 + m] <- bf16(att)
__global__ __launch_bounds__(256) void om_update(const float* __restrict__ att,
                                                 bf16* __restrict__ om_bf,
                                                 bf16* __restrict__ outs_bf, int t) {
  int i = blockIdx.x * 256 + threadIdx.x;  // 1048576
  int r = i >> 10, c = i & 1023;
  int b = r >> 9, mm = r & 511;
  bf16 v = __float2bfloat16(att[i]);
  om_bf[i] = v;
  outs_bf[((long)(b * 4096 + t * M_ + mm)) * D_ + c] = v;
}

// ---------------- launch ----------------
extern "C" void kernel_launch(void* const* d_in, const int* in_sizes, int n_in,
                              void* d_out, int out_size, void* d_ws, size_t ws_size,
                              hipStream_t stream) {
  (void)in_sizes; (void)n_in; (void)out_size; (void)ws_size;
  const void* x   = d_in[0];
  const void* fc  = d_in[1];
  const void* fs  = d_in[2];
  const void* wq  = d_in[3];
  const void* wk  = d_in[4];
  const void* wv  = d_in[5];
  const void* wo  = d_in[6];
  const void* wm  = d_in[7];
  const void* wkm = d_in[8];
  const void* wvm = d_in[9];
  const void* w1  = d_in[10];
  const void* w3  = d_in[11];
  const void* w2  = d_in[12];
  const void* fnw = d_in[13];
  const void* mnw = d_in[14];
  const void* om0 = d_in[15];

  char* p = (char*)d_ws;
  auto alloc = [&](size_t bytes) -> char* {
    char* r = p;
    p += (bytes + 255) & ~(size_t)255;
    return r;
  };
  // total ~158 MB
  int*   flag    = (int*)alloc(256);
  bf16*  wqkvT   = (bf16*)alloc((size_t)3 * 1048576 * 2);
  bf16*  wmT     = (bf16*)alloc((size_t)1048576 * 2);
  bf16*  wkmvmT  = (bf16*)alloc((size_t)2 * 1048576 * 2);
  bf16*  w13T    = (bf16*)alloc((size_t)2 * 2883584 * 2);
  bf16*  w2T     = (bf16*)alloc((size_t)2883584 * 2);
  bf16*  woT     = (bf16*)alloc((size_t)1048576 * 2);
  bf16*  xb      = (bf16*)alloc((size_t)8388608 * 2);
  float* cosf    = (float*)alloc((size_t)32768 * 4);
  float* sinf    = (float*)alloc((size_t)32768 * 4);
  float* ffnw    = (float*)alloc((size_t)1024 * 4);
  float* memw    = (float*)alloc((size_t)1024 * 4);
  bf16*  om_bf   = (bf16*)alloc((size_t)1048576 * 2);
  bf16*  outs_bf = (bf16*)alloc((size_t)8388608 * 2);
  float* qkvf    = (float*)alloc((size_t)3145728 * 4);
  float* om2a    = (float*)alloc((size_t)1048576 * 4);
  bf16*  h_bf    = (bf16*)alloc((size_t)1048576 * 2);
  float* g13     = (float*)alloc((size_t)5767168 * 4);
  bf16*  u_bf    = (bf16*)alloc((size_t)2883584 * 2);
  float* fbuf    = (float*)alloc((size_t)1048576 * 4);
  bf16*  om2_bf  = (bf16*)alloc((size_t)1048576 * 2);
  float* mkv     = (float*)alloc((size_t)2097152 * 4);
  float* qall    = (float*)alloc((size_t)1048576 * 4);
  float* kall    = (float*)alloc((size_t)2097152 * 4);
  float* vall    = (float*)alloc((size_t)2097152 * 4);
  float* att     = (float*)alloc((size_t)1048576 * 4);

  dim3 tb(256);
  probe_dtype<<<1, 64, 0, stream>>>(x, flag);

  transpose_cast<<<dim3(32, 32), tb, 0, stream>>>(wq, wqkvT, 1024, 1024, flag);
  transpose_cast<<<dim3(32, 32), tb, 0, stream>>>(wk, wqkvT + 1048576, 1024, 1024, flag);
  transpose_cast<<<dim3(32, 32), tb, 0, stream>>>(wv, wqkvT + 2 * 1048576, 1024, 1024, flag);
  transpose_cast<<<dim3(32, 32), tb, 0, stream>>>(wm, wmT, 1024, 1024, flag);
  transpose_cast<<<dim3(32, 32), tb, 0, stream>>>(wkm, wkmvmT, 1024, 1024, flag);
  transpose_cast<<<dim3(32, 32), tb, 0, stream>>>(wvm, wkmvmT + 1048576, 1024, 1024, flag);
  transpose_cast<<<dim3(88, 32), tb, 0, stream>>>(w1, w13T, 1024, 2816, flag);
  transpose_cast<<<dim3(88, 32), tb, 0, stream>>>(w3, w13T + 2883584, 1024, 2816, flag);
  transpose_cast<<<dim3(32, 88), tb, 0, stream>>>(w2, w2T, 2816, 1024, flag);
  transpose_cast<<<dim3(32, 32), tb, 0, stream>>>(wo, woT, 1024, 1024, flag);

  cast_to_bf16<<<32768, tb, 0, stream>>>(x, xb, 8388608, flag);
  cast_to_f32<<<128, tb, 0, stream>>>(fc, cosf, 32768, flag);
  cast_to_f32<<<128, tb, 0, stream>>>(fs, sinf, 32768, flag);
  cast_to_f32<<<4, tb, 0, stream>>>(fnw, ffnw, 1024, flag);
  cast_to_f32<<<4, tb, 0, stream>>>(mnw, memw, 1024, flag);
  init_om<<<4096, tb, 0, stream>>>(om0, om_bf, flag);

  for (int t = 0; t < NSTEP; ++t) {
    // xq|xk|xv = subx @ [wq|wk|wv]
    gemm_bf16<<<dim3(48, 16), tb, 0, stream>>>(xb, wqkvT, qkvf, nullptr, flag,
                                               1024, 3072, 1024, 512, 4096, t * 512, 0);
    // om2a = om @ wm
    gemm_bf16<<<dim3(16, 16), tb, 0, stream>>>(om_bf, wmT, om2a, nullptr, flag,
                                               1024, 1024, 1024, 1024, 1024, 0, 0);
    rmsnorm_cast<<<1024, tb, 0, stream>>>(om2a, ffnw, h_bf, nullptr);
    // g1|g3 = h @ [w1|w3]
    gemm_bf16<<<dim3(88, 16), tb, 0, stream>>>(h_bf, w13T, g13, nullptr, flag,
                                               1024, 5632, 1024, 1024, 1024, 0, 0);
    silu_mul_cast<<<dim3(11, 1024), tb, 0, stream>>>(g13, u_bf);
    // f = u @ w2
    gemm_bf16<<<dim3(16, 16), tb, 0, stream>>>(u_bf, w2T, fbuf, nullptr, flag,
                                               1024, 1024, 2816, 1024, 1024, 0, 0);
    // om2 = rmsnorm(om2a + f, mem_norm_w)
    rmsnorm_cast<<<1024, tb, 0, stream>>>(om2a, memw, om2_bf, fbuf);
    // mk|mv = om2 @ [wkm|wvm]
    gemm_bf16<<<dim3(32, 16), tb, 0, stream>>>(om2_bf, wkmvmT, mkv, nullptr, flag,
                                               1024, 2048, 1024, 1024, 1024, 0, 0);
    rope_build<<<4096, tb, 0, stream>>>(qkvf, mkv, cosf, sinf, qall, kall, vall);
    attn_kernel<<<4096, tb, 0, stream>>>(qall, kall, vall, att);
    om_update<<<4096, tb, 0, stream>>>(att, om_bf, outs_bf, t);
  }
  // final: y = outs @ wo -> d_out (dtype per flag)
  gemm_bf16<<<dim3(16, 128), tb, 0, stream>>>(outs_bf, woT, nullptr, d_out, flag,
                                              8192, 1024, 1024, 8192, 8192, 0, 1);
}

// Round 2
// 3643.115 us; speedup vs baseline: 2.6982x; 2.6982x over previous
//
#include <hip/hip_runtime.h>
#include <hip/hip_bf16.h>

// Problem: B=2, S=4096, D=1024, H=16, HD=64, M=512, L=1024, HID=2816, 8 scan steps.
// R1: attention was 96% of runtime (latency-bound wave-per-query). R2: fp32
// flash attention, thread-per-query, key-split x8 for parallelism, LDS K/V tiles,
// no cross-lane reductions. Numerics identical to R1 (fp32 attention) to hold
// absmax at 0.03125 (threshold 0.0339).

#define D_    1024
#define H_    16
#define HD_   64
#define M_    512
#define L_    1024
#define HID_  2816
#define NSTEP 8
#define KC    8     // key chunks (parallel split)
#define CK    128   // keys per chunk
#define KT    32    // keys per LDS tile

typedef __hip_bfloat16 bf16;
typedef __attribute__((ext_vector_type(8))) short short8;
typedef __attribute__((ext_vector_type(4))) float floatx4;

// ---------------- dtype probe ----------------
__global__ void probe_dtype(const void* x, int* flag) {
  int lane = threadIdx.x;
  unsigned short v = ((const unsigned short*)x)[2 * lane];
  int e = (v >> 7) & 0xFF;
  bool sane = (e >= 100 && e <= 140);
  unsigned long long m = __ballot(sane);
  if (lane == 0) flag[0] = (__popcll(m) >= 40) ? 1 : 0;  // 1 = bf16 inputs
}

__device__ __forceinline__ float load_any(const void* p, long i, int isbf) {
  return isbf ? __bfloat162float(((const bf16*)p)[i]) : ((const float*)p)[i];
}

// ---------------- converts ----------------
__global__ __launch_bounds__(256) void transpose_cast(const void* in, bf16* out,
                                                      int K, int N, const int* flagp) {
  __shared__ float tile[32][33];
  int isbf = flagp[0];
  int tx = threadIdx.x & 31, ty = threadIdx.x >> 5;
  int n = blockIdx.x * 32 + tx;
#pragma unroll
  for (int i = 0; i < 4; i++) {
    int k = blockIdx.y * 32 + ty + i * 8;
    tile[ty + i * 8][tx] = load_any(in, (long)k * N + n, isbf);
  }
  __syncthreads();
  int k2 = blockIdx.y * 32 + tx;
#pragma unroll
  for (int i = 0; i < 4; i++) {
    int n2 = blockIdx.x * 32 + ty + i * 8;
    out[(long)n2 * K + k2] = __float2bfloat16(tile[tx][ty + i * 8]);
  }
}

__global__ __launch_bounds__(256) void cast_to_bf16(const void* in, bf16* out, int n,
                                                    const int* flagp) {
  int i = blockIdx.x * 256 + threadIdx.x;
  if (i < n) out[i] = __float2bfloat16(load_any(in, i, flagp[0]));
}

__global__ __launch_bounds__(256) void cast_to_f32(const void* in, float* out, int n,
                                                   const int* flagp) {
  int i = blockIdx.x * 256 + threadIdx.x;
  if (i < n) out[i] = load_any(in, i, flagp[0]);
}

__global__ __launch_bounds__(256) void init_om(const void* in, bf16* om, const int* flagp) {
  int i = blockIdx.x * 256 + threadIdx.x;  // 1048576
  int rem = i & (M_ * D_ - 1);
  om[i] = __float2bfloat16(load_any(in, rem, flagp[0]));
}

// ---------------- MFMA GEMM (unchanged from R1) ----------------
__global__ __launch_bounds__(256) void gemm_bf16(
    const bf16* __restrict__ A, const bf16* __restrict__ WT, float* __restrict__ Cf,
    void* __restrict__ dout, const int* __restrict__ flagp, int Mrows, int N, int K,
    int row_inner, int row_outer, int row_off, int to_dout) {
  __shared__ char smem[16384];
  char* aT = smem;
  char* bT = smem + 8192;
  int tid = threadIdx.x;
  int C0 = blockIdx.x * 64, R0 = blockIdx.y * 64;
  int wave = tid >> 6, lane = tid & 63;
  int wm_ = wave >> 1, wn_ = wave & 1;
  floatx4 acc[2][2] = {};

  int q0 = tid, q1 = tid + 256;
  int am0 = q0 >> 3, ac0 = q0 & 7;
  int am1 = q1 >> 3, ac1 = q1 & 7;
  int r0 = R0 + am0, r1 = R0 + am1;
  long grow0 = (long)(r0 / row_inner) * row_outer + row_off + (r0 % row_inner);
  long grow1 = (long)(r1 / row_inner) * row_outer + row_off + (r1 % row_inner);
  long bn0 = (long)(C0 + am0) * K, bn1 = (long)(C0 + am1) * K;
  int lofa0 = (am0 * 8 + (ac0 ^ (am0 & 7))) * 16;
  int lofa1 = (am1 * 8 + (ac1 ^ (am1 & 7))) * 16;

  for (int k0 = 0; k0 < K; k0 += 64) {
    uint4 va0 = *(const uint4*)(A + grow0 * K + k0 + ac0 * 8);
    uint4 va1 = *(const uint4*)(A + grow1 * K + k0 + ac1 * 8);
    uint4 vb0 = *(const uint4*)(WT + bn0 + k0 + ac0 * 8);
    uint4 vb1 = *(const uint4*)(WT + bn1 + k0 + ac1 * 8);
    __syncthreads();
    *(uint4*)(aT + lofa0) = va0;
    *(uint4*)(aT + lofa1) = va1;
    *(uint4*)(bT + lofa0) = vb0;
    *(uint4*)(bT + lofa1) = vb1;
    __syncthreads();
#pragma unroll
    for (int kki = 0; kki < 2; ++kki) {
      int cbase = kki * 4 + (lane >> 4);
      short8 af[2], bfr[2];
#pragma unroll
      for (int i = 0; i < 2; ++i) {
        int ml = wm_ * 32 + i * 16 + (lane & 15);
        af[i] = *(const short8*)(aT + (ml * 8 + (cbase ^ (ml & 7))) * 16);
        int nl = wn_ * 32 + i * 16 + (lane & 15);
        bfr[i] = *(const short8*)(bT + (nl * 8 + (cbase ^ (nl & 7))) * 16);
      }
#pragma unroll
      for (int i = 0; i < 2; ++i)
#pragma unroll
        for (int j = 0; j < 2; ++j)
          acc[i][j] = __builtin_amdgcn_mfma_f32_16x16x32_bf16(af[i], bfr[j], acc[i][j], 0, 0, 0);
    }
  }
  int isbf = flagp[0];
#pragma unroll
  for (int i = 0; i < 2; ++i)
#pragma unroll
    for (int j = 0; j < 2; ++j) {
      int row = R0 + wm_ * 32 + i * 16 + (lane >> 4) * 4;
      int col = C0 + wn_ * 32 + j * 16 + (lane & 15);
#pragma unroll
      for (int rg = 0; rg < 4; ++rg) {
        float v = acc[i][j][rg];
        long off = (long)(row + rg) * N + col;
        if (to_dout) {
          if (isbf) ((bf16*)dout)[off] = __float2bfloat16(v);
          else ((float*)dout)[off] = v;
        } else {
          Cf[off] = v;
        }
      }
    }
}

// ---------------- elementwise ----------------
__global__ __launch_bounds__(256) void rmsnorm_cast(const float* __restrict__ X,
                                                    const float* __restrict__ Wn,
                                                    bf16* __restrict__ Y,
                                                    const float* __restrict__ Xadd) {
  int row = blockIdx.x, tid = threadIdx.x;
  const float* xr = X + (long)row * D_;
  float vals[4], ss = 0.f;
#pragma unroll
  for (int i = 0; i < 4; i++) {
    int c = tid + i * 256;
    float v = xr[c];
    if (Xadd) v += Xadd[(long)row * D_ + c];
    vals[i] = v;
    ss += v * v;
  }
#pragma unroll
  for (int off = 32; off; off >>= 1) ss += __shfl_xor(ss, off);
  __shared__ float wsum[4];
  int wv = tid >> 6, lane = tid & 63;
  if (lane == 0) wsum[wv] = ss;
  __syncthreads();
  ss = wsum[0] + wsum[1] + wsum[2] + wsum[3];
  float r = rsqrtf(ss * (1.0f / D_) + 1e-5f);
#pragma unroll
  for (int i = 0; i < 4; i++) {
    int c = tid + i * 256;
    Y[(long)row * D_ + c] = __float2bfloat16(vals[i] * r * Wn[c]);
  }
}

__global__ __launch_bounds__(256) void silu_mul_cast(const float* __restrict__ g13,
                                                     bf16* __restrict__ u) {
  int c = blockIdx.x * 256 + threadIdx.x;  // 0..2815
  int r = blockIdx.y;
  float a = g13[(long)r * (2 * HID_) + c];
  float b = g13[(long)r * (2 * HID_) + HID_ + c];
  float s = a / (1.f + __expf(-a));
  u[(long)r * HID_ + c] = __float2bfloat16(s * b);
}

__global__ __launch_bounds__(256) void rope_build(
    const float* __restrict__ qkvf, const float* __restrict__ mkv,
    const float* __restrict__ cosf, const float* __restrict__ sinf,
    float* __restrict__ qall, float* __restrict__ kall, float* __restrict__ vall) {
  int idx = blockIdx.x * 256 + threadIdx.x;  // 1048576
  int i = idx & 31;
  int pos = (idx >> 5) & 1023;
  int bh = idx >> 15;  // 0..31
  int b = bh >> 4, h = bh & 15;
  float c = cosf[pos * 32 + i], s = sinf[pos * 32 + i];
  float k0, k1, v0, v1;
  if (pos < M_) {
    long base = ((long)(b * M_ + pos)) * 2048 + h * HD_ + 2 * i;
    k0 = mkv[base]; k1 = mkv[base + 1];
    v0 = mkv[base + 1024]; v1 = mkv[base + 1025];
  } else {
    long base = ((long)(b * M_ + pos - M_)) * 3072 + 1024 + h * HD_ + 2 * i;
    k0 = qkvf[base]; k1 = qkvf[base + 1];
    v0 = qkvf[base + 1024]; v1 = qkvf[base + 1025];
  }
  long ko = ((long)bh) * (L_ * HD_) + pos * HD_ + 2 * i;
  kall[ko] = k0 * c - k1 * s;
  kall[ko + 1] = k0 * s + k1 * c;
  vall[ko] = v0;
  vall[ko + 1] = v1;
  if (pos >= M_) {
    long qbase = ((long)(b * M_ + pos - M_)) * 3072 + h * HD_ + 2 * i;
    float q0 = qkvf[qbase], q1 = qkvf[qbase + 1];
    long qo = ((long)bh) * (M_ * HD_) + (pos - M_) * HD_ + 2 * i;
    qall[qo] = q0 * c - q1 * s;
    qall[qo + 1] = q0 * s + q1 * c;
  }
}

// ---------------- flash attention, fp32 VALU ----------------
// grid (qb=2, kc=8, bh=32); 256 threads, thread = one x-query (pos P=512+q).
// K/V tiles 32x64 fp32 in LDS (stride 68 words -> 2-way bank alias on staging
// writes = free); scores/PV are register FMAs with broadcast ds_read_b128.
// Partials (m, l, unnormalized o) per key-chunk; merged by attn_merge.
__global__ __launch_bounds__(256) void attn_partial(
    const float* __restrict__ qall, const float* __restrict__ kall,
    const float* __restrict__ vall, float* __restrict__ opart,
    float* __restrict__ mpart, float* __restrict__ lpart) {
  __shared__ float Kt[KT][68];
  __shared__ float Vt[KT][68];
  int qb = blockIdx.x, kc = blockIdx.y, bh = blockIdx.z;
  int tid = threadIdx.x;
  int q = qb * 256 + tid;     // 0..511
  int P = M_ + q;
  int k0g = kc * CK;
  long pidx = ((long)kc * 32 + bh) * 512 + q;

  int qmax = qb * 256 + 255;
  if (k0g > M_ + qmax) {      // whole block causally empty
    mpart[pidx] = -1e30f;
    lpart[pidx] = 0.f;
    return;
  }

  // q fragment (pre-scaled by 1/sqrt(HD))
  float4 qr[16];
  const float* qp = qall + (long)bh * (M_ * HD_) + (long)q * HD_;
#pragma unroll
  for (int d4 = 0; d4 < 16; ++d4) {
    float4 v = *(const float4*)(qp + d4 * 4);
    qr[d4].x = v.x * 0.125f; qr[d4].y = v.y * 0.125f;
    qr[d4].z = v.z * 0.125f; qr[d4].w = v.w * 0.125f;
  }
  float4 accr[16];
#pragma unroll
  for (int d4 = 0; d4 < 16; ++d4) accr[d4] = make_float4(0.f, 0.f, 0.f, 0.f);
  float m = -1e30f, l = 0.f;

  int sj = tid >> 3, sd = (tid & 7) * 8;  // staging coords
  const float* kgb = kall + (long)bh * (L_ * HD_);
  const float* vgb = vall + (long)bh * (L_ * HD_);

  for (int kt = 0; kt < CK / KT; ++kt) {
    int kbase = k0g + kt * KT;
    const float* kg = kgb + (long)(kbase + sj) * HD_ + sd;
    const float* vg = vgb + (long)(kbase + sj) * HD_ + sd;
    float4 k0v = *(const float4*)kg;
    float4 k1v = *(const float4*)(kg + 4);
    float4 v0v = *(const float4*)vg;
    float4 v1v = *(const float4*)(vg + 4);
    __syncthreads();
    *(float4*)&Kt[sj][sd] = k0v;
    *(float4*)&Kt[sj][sd + 4] = k1v;
    *(float4*)&Vt[sj][sd] = v0v;
    *(float4*)&Vt[sj][sd + 4] = v1v;
    __syncthreads();

    float s[KT];
#pragma unroll
    for (int j = 0; j < KT; ++j) s[j] = 0.f;
#pragma unroll
    for (int d4 = 0; d4 < 16; ++d4) {
      float4 qv = qr[d4];
#pragma unroll
      for (int j = 0; j < KT; ++j) {
        float4 kv = *(const float4*)&Kt[j][d4 * 4];
        s[j] += qv.x * kv.x + qv.y * kv.y + qv.z * kv.z + qv.w * kv.w;
      }
    }
    // causal mask + tile max
    float smax = -1e30f;
#pragma unroll
    for (int j = 0; j < KT; ++j) {
      if (kbase + j > P) s[j] = -1e30f;
      smax = fmaxf(smax, s[j]);
    }
    float newm = fmaxf(m, smax);
    float corr = __expf(m - newm);
    float p[KT];
    float lsum = 0.f;
#pragma unroll
    for (int j = 0; j < KT; ++j) {
      float pj = (s[j] > -0.9e30f) ? __expf(s[j] - newm) : 0.f;
      p[j] = pj;
      lsum += pj;
    }
    m = newm;
    l = l * corr + lsum;
#pragma unroll
    for (int d4 = 0; d4 < 16; ++d4) {
      accr[d4].x *= corr; accr[d4].y *= corr;
      accr[d4].z *= corr; accr[d4].w *= corr;
    }
    for (int j = 0; j < KT; ++j) {
      float pj = p[j];
#pragma unroll
      for (int d4 = 0; d4 < 16; ++d4) {
        float4 vv = *(const float4*)&Vt[j][d4 * 4];
        accr[d4].x += pj * vv.x; accr[d4].y += pj * vv.y;
        accr[d4].z += pj * vv.z; accr[d4].w += pj * vv.w;
      }
    }
  }

  mpart[pidx] = m;
  lpart[pidx] = l;
  float* op = opart + pidx * 64;
#pragma unroll
  for (int d4 = 0; d4 < 16; ++d4) *(float4*)(op + d4 * 4) = accr[d4];
}

// merge 8 chunk-partials; writes om_bf and outs_bf directly (fuses om_update).
__global__ __launch_bounds__(256) void attn_merge(
    const float* __restrict__ opart, const float* __restrict__ mpart,
    const float* __restrict__ lpart, bf16* __restrict__ om_bf,
    bf16* __restrict__ outs_bf, int t) {
  int idx = blockIdx.x * 256 + threadIdx.x;  // 1048576
  int d = idx & 63;
  int q = (idx >> 6) & 511;
  int bh = idx >> 15;
  long rp = (long)bh * 512 + q;
  float ms[KC];
  float M = -1e30f;
#pragma unroll
  for (int c = 0; c < KC; ++c) {
    ms[c] = mpart[(long)c * 16384 + rp];
    M = fmaxf(M, ms[c]);
  }
  float num = 0.f, den = 0.f;
#pragma unroll
  for (int c = 0; c < KC; ++c) {
    float w = __expf(ms[c] - M);
    den += w * lpart[(long)c * 16384 + rp];
    num += w * opart[((long)c * 16384 + rp) * 64 + d];
  }
  float out = num / den;
  int b = bh >> 4, h = bh & 15;
  bf16 v = __float2bfloat16(out);
  om_bf[((long)(b * 512 + q)) * 1024 + h * 64 + d] = v;
  outs_bf[((long)(b * 4096 + t * 512 + q)) * 1024 + h * 64 + d] = v;
}

// ---------------- launch ----------------
extern "C" void kernel_launch(void* const* d_in, const int* in_sizes, int n_in,
                              void* d_out, int out_size, void* d_ws, size_t ws_size,
                              hipStream_t stream) {
  (void)in_sizes; (void)n_in; (void)out_size; (void)ws_size;
  const void* x   = d_in[0];
  const void* fc  = d_in[1];
  const void* fs  = d_in[2];
  const void* wq  = d_in[3];
  const void* wk  = d_in[4];
  const void* wv  = d_in[5];
  const void* wo  = d_in[6];
  const void* wm  = d_in[7];
  const void* wkm = d_in[8];
  const void* wvm = d_in[9];
  const void* w1  = d_in[10];
  const void* w3  = d_in[11];
  const void* w2  = d_in[12];
  const void* fnw = d_in[13];
  const void* mnw = d_in[14];
  const void* om0 = d_in[15];

  char* p = (char*)d_ws;
  auto alloc = [&](size_t bytes) -> char* {
    char* r = p;
    p += (bytes + 255) & ~(size_t)255;
    return r;
  };
  int*   flag    = (int*)alloc(256);
  bf16*  wqkvT   = (bf16*)alloc((size_t)3 * 1048576 * 2);
  bf16*  wmT     = (bf16*)alloc((size_t)1048576 * 2);
  bf16*  wkmvmT  = (bf16*)alloc((size_t)2 * 1048576 * 2);
  bf16*  w13T    = (bf16*)alloc((size_t)2 * 2883584 * 2);
  bf16*  w2T     = (bf16*)alloc((size_t)2883584 * 2);
  bf16*  woT     = (bf16*)alloc((size_t)1048576 * 2);
  bf16*  xb      = (bf16*)alloc((size_t)8388608 * 2);
  float* cosf    = (float*)alloc((size_t)32768 * 4);
  float* sinf    = (float*)alloc((size_t)32768 * 4);
  float* ffnw    = (float*)alloc((size_t)1024 * 4);
  float* memw    = (float*)alloc((size_t)1024 * 4);
  bf16*  om_bf   = (bf16*)alloc((size_t)1048576 * 2);
  bf16*  outs_bf = (bf16*)alloc((size_t)8388608 * 2);
  float* qkvf    = (float*)alloc((size_t)3145728 * 4);
  float* om2a    = (float*)alloc((size_t)1048576 * 4);
  bf16*  h_bf    = (bf16*)alloc((size_t)1048576 * 2);
  // g13 (23.1 MB, dead during attention) aliases opart (33.5 MB)
  char*  shared_ = alloc((size_t)KC * 32 * 512 * 64 * 4);
  float* g13     = (float*)shared_;
  float* opart   = (float*)shared_;
  bf16*  u_bf    = (bf16*)alloc((size_t)2883584 * 2);
  float* fbuf    = (float*)alloc((size_t)1048576 * 4);
  bf16*  om2_bf  = (bf16*)alloc((size_t)1048576 * 2);
  float* mkv     = (float*)alloc((size_t)2097152 * 4);
  float* qall    = (float*)alloc((size_t)1048576 * 4);
  float* kall    = (float*)alloc((size_t)2097152 * 4);
  float* vall    = (float*)alloc((size_t)2097152 * 4);
  float* mpart   = (float*)alloc((size_t)KC * 32 * 512 * 4);
  float* lpart   = (float*)alloc((size_t)KC * 32 * 512 * 4);

  dim3 tb(256);
  probe_dtype<<<1, 64, 0, stream>>>(x, flag);

  transpose_cast<<<dim3(32, 32), tb, 0, stream>>>(wq, wqkvT, 1024, 1024, flag);
  transpose_cast<<<dim3(32, 32), tb, 0, stream>>>(wk, wqkvT + 1048576, 1024, 1024, flag);
  transpose_cast<<<dim3(32, 32), tb, 0, stream>>>(wv, wqkvT + 2 * 1048576, 1024, 1024, flag);
  transpose_cast<<<dim3(32, 32), tb, 0, stream>>>(wm, wmT, 1024, 1024, flag);
  transpose_cast<<<dim3(32, 32), tb, 0, stream>>>(wkm, wkmvmT, 1024, 1024, flag);
  transpose_cast<<<dim3(32, 32), tb, 0, stream>>>(wvm, wkmvmT + 1048576, 1024, 1024, flag);
  transpose_cast<<<dim3(88, 32), tb, 0, stream>>>(w1, w13T, 1024, 2816, flag);
  transpose_cast<<<dim3(88, 32), tb, 0, stream>>>(w3, w13T + 2883584, 1024, 2816, flag);
  transpose_cast<<<dim3(32, 88), tb, 0, stream>>>(w2, w2T, 2816, 1024, flag);
  transpose_cast<<<dim3(32, 32), tb, 0, stream>>>(wo, woT, 1024, 1024, flag);

  cast_to_bf16<<<32768, tb, 0, stream>>>(x, xb, 8388608, flag);
  cast_to_f32<<<128, tb, 0, stream>>>(fc, cosf, 32768, flag);
  cast_to_f32<<<128, tb, 0, stream>>>(fs, sinf, 32768, flag);
  cast_to_f32<<<4, tb, 0, stream>>>(fnw, ffnw, 1024, flag);
  cast_to_f32<<<4, tb, 0, stream>>>(mnw, memw, 1024, flag);
  init_om<<<4096, tb, 0, stream>>>(om0, om_bf, flag);

  for (int t = 0; t < NSTEP; ++t) {
    gemm_bf16<<<dim3(48, 16), tb, 0, stream>>>(xb, wqkvT, qkvf, nullptr, flag,
                                               1024, 3072, 1024, 512, 4096, t * 512, 0);
    gemm_bf16<<<dim3(16, 16), tb, 0, stream>>>(om_bf, wmT, om2a, nullptr, flag,
                                               1024, 1024, 1024, 1024, 1024, 0, 0);
    rmsnorm_cast<<<1024, tb, 0, stream>>>(om2a, ffnw, h_bf, nullptr);
    gemm_bf16<<<dim3(88, 16), tb, 0, stream>>>(h_bf, w13T, g13, nullptr, flag,
                                               1024, 5632, 1024, 1024, 1024, 0, 0);
    silu_mul_cast<<<dim3(11, 1024), tb, 0, stream>>>(g13, u_bf);
    gemm_bf16<<<dim3(16, 16), tb, 0, stream>>>(u_bf, w2T, fbuf, nullptr, flag,
                                               1024, 1024, 2816, 1024, 1024, 0, 0);
    rmsnorm_cast<<<1024, tb, 0, stream>>>(om2a, memw, om2_bf, fbuf);
    gemm_bf16<<<dim3(32, 16), tb, 0, stream>>>(om2_bf, wkmvmT, mkv, nullptr, flag,
                                               1024, 2048, 1024, 1024, 1024, 0, 0);
    rope_build<<<4096, tb, 0, stream>>>(qkvf, mkv, cosf, sinf, qall, kall, vall);
    attn_partial<<<dim3(2, KC, 32), tb, 0, stream>>>(qall, kall, vall, opart, mpart, lpart);
    attn_merge<<<4096, tb, 0, stream>>>(opart, mpart, lpart, om_bf, outs_bf, t);
  }
  gemm_bf16<<<dim3(16, 128), tb, 0, stream>>>(outs_bf, woT, nullptr, d_out, flag,
                                              8192, 1024, 1024, 8192, 8192, 0, 1);
}

// Round 3
// 1318.272 us; speedup vs baseline: 7.4567x; 2.7636x over previous
//
#include <hip/hip_runtime.h>
#include <hip/hip_bf16.h>

// B=2, S=4096, D=1024, H=16, HD=64, M=512, L=1024, HID=2816, 8 scan steps.
// R1: wave-per-query attention latency-bound (9.4 ms). R2: fp32 flash, but
// 256-VGPR spills (WRITE_SIZE 84MB/dispatch, VALUBusy 17%) -> 2.55 ms attn.
// R3: fp16 MFMA flash attention (fp32 softmax + fp32 accum; fp16 rounding
// ~2^-11 keeps absmax margin), S^T orientation so softmax is per-lane.

#define D_    1024
#define H_    16
#define HD_   64
#define M_    512
#define L_    1024
#define HID_  2816
#define NSTEP 8

typedef __hip_bfloat16 bf16;
typedef _Float16 f16;
typedef __attribute__((ext_vector_type(8))) short short8;
typedef __attribute__((ext_vector_type(8))) _Float16 f16x8;
typedef __attribute__((ext_vector_type(2))) _Float16 f16x2;
typedef __attribute__((ext_vector_type(4))) float floatx4;

// ---------------- dtype probe ----------------
__global__ void probe_dtype(const void* x, int* flag) {
  int lane = threadIdx.x;
  unsigned short v = ((const unsigned short*)x)[2 * lane];
  int e = (v >> 7) & 0xFF;
  bool sane = (e >= 100 && e <= 140);
  unsigned long long m = __ballot(sane);
  if (lane == 0) flag[0] = (__popcll(m) >= 40) ? 1 : 0;  // 1 = bf16 inputs
}

__device__ __forceinline__ float load_any(const void* p, long i, int isbf) {
  return isbf ? __bfloat162float(((const bf16*)p)[i]) : ((const float*)p)[i];
}

// ---------------- converts ----------------
__global__ __launch_bounds__(256) void transpose_cast(const void* in, bf16* out,
                                                      int K, int N, const int* flagp) {
  __shared__ float tile[32][33];
  int isbf = flagp[0];
  int tx = threadIdx.x & 31, ty = threadIdx.x >> 5;
  int n = blockIdx.x * 32 + tx;
#pragma unroll
  for (int i = 0; i < 4; i++) {
    int k = blockIdx.y * 32 + ty + i * 8;
    tile[ty + i * 8][tx] = load_any(in, (long)k * N + n, isbf);
  }
  __syncthreads();
  int k2 = blockIdx.y * 32 + tx;
#pragma unroll
  for (int i = 0; i < 4; i++) {
    int n2 = blockIdx.x * 32 + ty + i * 8;
    out[(long)n2 * K + k2] = __float2bfloat16(tile[tx][ty + i * 8]);
  }
}

__global__ __launch_bounds__(256) void cast_to_bf16(const void* in, bf16* out, int n,
                                                    const int* flagp) {
  int i = blockIdx.x * 256 + threadIdx.x;
  if (i < n) out[i] = __float2bfloat16(load_any(in, i, flagp[0]));
}

__global__ __launch_bounds__(256) void cast_to_f32(const void* in, float* out, int n,
                                                   const int* flagp) {
  int i = blockIdx.x * 256 + threadIdx.x;
  if (i < n) out[i] = load_any(in, i, flagp[0]);
}

__global__ __launch_bounds__(256) void init_om(const void* in, bf16* om, const int* flagp) {
  int i = blockIdx.x * 256 + threadIdx.x;  // 1048576
  int rem = i & (M_ * D_ - 1);
  om[i] = __float2bfloat16(load_any(in, rem, flagp[0]));
}

// ---------------- MFMA GEMM (unchanged) ----------------
__global__ __launch_bounds__(256) void gemm_bf16(
    const bf16* __restrict__ A, const bf16* __restrict__ WT, float* __restrict__ Cf,
    void* __restrict__ dout, const int* __restrict__ flagp, int Mrows, int N, int K,
    int row_inner, int row_outer, int row_off, int to_dout) {
  __shared__ char smem[16384];
  char* aT = smem;
  char* bT = smem + 8192;
  int tid = threadIdx.x;
  int C0 = blockIdx.x * 64, R0 = blockIdx.y * 64;
  int wave = tid >> 6, lane = tid & 63;
  int wm_ = wave >> 1, wn_ = wave & 1;
  floatx4 acc[2][2] = {};

  int q0 = tid, q1 = tid + 256;
  int am0 = q0 >> 3, ac0 = q0 & 7;
  int am1 = q1 >> 3, ac1 = q1 & 7;
  int r0 = R0 + am0, r1 = R0 + am1;
  long grow0 = (long)(r0 / row_inner) * row_outer + row_off + (r0 % row_inner);
  long grow1 = (long)(r1 / row_inner) * row_outer + row_off + (r1 % row_inner);
  long bn0 = (long)(C0 + am0) * K, bn1 = (long)(C0 + am1) * K;
  int lofa0 = (am0 * 8 + (ac0 ^ (am0 & 7))) * 16;
  int lofa1 = (am1 * 8 + (ac1 ^ (am1 & 7))) * 16;

  for (int k0 = 0; k0 < K; k0 += 64) {
    uint4 va0 = *(const uint4*)(A + grow0 * K + k0 + ac0 * 8);
    uint4 va1 = *(const uint4*)(A + grow1 * K + k0 + ac1 * 8);
    uint4 vb0 = *(const uint4*)(WT + bn0 + k0 + ac0 * 8);
    uint4 vb1 = *(const uint4*)(WT + bn1 + k0 + ac1 * 8);
    __syncthreads();
    *(uint4*)(aT + lofa0) = va0;
    *(uint4*)(aT + lofa1) = va1;
    *(uint4*)(bT + lofa0) = vb0;
    *(uint4*)(bT + lofa1) = vb1;
    __syncthreads();
#pragma unroll
    for (int kki = 0; kki < 2; ++kki) {
      int cbase = kki * 4 + (lane >> 4);
      short8 af[2], bfr[2];
#pragma unroll
      for (int i = 0; i < 2; ++i) {
        int ml = wm_ * 32 + i * 16 + (lane & 15);
        af[i] = *(const short8*)(aT + (ml * 8 + (cbase ^ (ml & 7))) * 16);
        int nl = wn_ * 32 + i * 16 + (lane & 15);
        bfr[i] = *(const short8*)(bT + (nl * 8 + (cbase ^ (nl & 7))) * 16);
      }
#pragma unroll
      for (int i = 0; i < 2; ++i)
#pragma unroll
        for (int j = 0; j < 2; ++j)
          acc[i][j] = __builtin_amdgcn_mfma_f32_16x16x32_bf16(af[i], bfr[j], acc[i][j], 0, 0, 0);
    }
  }
  int isbf = flagp[0];
#pragma unroll
  for (int i = 0; i < 2; ++i)
#pragma unroll
    for (int j = 0; j < 2; ++j) {
      int row = R0 + wm_ * 32 + i * 16 + (lane >> 4) * 4;
      int col = C0 + wn_ * 32 + j * 16 + (lane & 15);
#pragma unroll
      for (int rg = 0; rg < 4; ++rg) {
        float v = acc[i][j][rg];
        long off = (long)(row + rg) * N + col;
        if (to_dout) {
          if (isbf) ((bf16*)dout)[off] = __float2bfloat16(v);
          else ((float*)dout)[off] = v;
        } else {
          Cf[off] = v;
        }
      }
    }
}

// ---------------- elementwise ----------------
__global__ __launch_bounds__(256) void rmsnorm_cast(const float* __restrict__ X,
                                                    const float* __restrict__ Wn,
                                                    bf16* __restrict__ Y,
                                                    const float* __restrict__ Xadd) {
  int row = blockIdx.x, tid = threadIdx.x;
  const float* xr = X + (long)row * D_;
  float vals[4], ss = 0.f;
#pragma unroll
  for (int i = 0; i < 4; i++) {
    int c = tid + i * 256;
    float v = xr[c];
    if (Xadd) v += Xadd[(long)row * D_ + c];
    vals[i] = v;
    ss += v * v;
  }
#pragma unroll
  for (int off = 32; off; off >>= 1) ss += __shfl_xor(ss, off);
  __shared__ float wsum[4];
  int wv = tid >> 6, lane = tid & 63;
  if (lane == 0) wsum[wv] = ss;
  __syncthreads();
  ss = wsum[0] + wsum[1] + wsum[2] + wsum[3];
  float r = rsqrtf(ss * (1.0f / D_) + 1e-5f);
#pragma unroll
  for (int i = 0; i < 4; i++) {
    int c = tid + i * 256;
    Y[(long)row * D_ + c] = __float2bfloat16(vals[i] * r * Wn[c]);
  }
}

__global__ __launch_bounds__(256) void silu_mul_cast(const float* __restrict__ g13,
                                                     bf16* __restrict__ u) {
  int c = blockIdx.x * 256 + threadIdx.x;  // 0..2815
  int r = blockIdx.y;
  float a = g13[(long)r * (2 * HID_) + c];
  float b = g13[(long)r * (2 * HID_) + HID_ + c];
  float s = a / (1.f + __expf(-a));
  u[(long)r * HID_ + c] = __float2bfloat16(s * b);
}

// rope -> fp16 q (pre-scaled by 1/8), k, v. Layout [bh][pos][64].
__global__ __launch_bounds__(256) void rope_build(
    const float* __restrict__ qkvf, const float* __restrict__ mkv,
    const float* __restrict__ cosf, const float* __restrict__ sinf,
    f16* __restrict__ qh, f16* __restrict__ kh, f16* __restrict__ vh) {
  int idx = blockIdx.x * 256 + threadIdx.x;  // 1048576
  int i = idx & 31;
  int pos = (idx >> 5) & 1023;
  int bh = idx >> 15;  // 0..31
  int b = bh >> 4, h = bh & 15;
  float c = cosf[pos * 32 + i], s = sinf[pos * 32 + i];
  float k0, k1, v0, v1;
  if (pos < M_) {
    long base = ((long)(b * M_ + pos)) * 2048 + h * HD_ + 2 * i;
    k0 = mkv[base]; k1 = mkv[base + 1];
    v0 = mkv[base + 1024]; v1 = mkv[base + 1025];
  } else {
    long base = ((long)(b * M_ + pos - M_)) * 3072 + 1024 + h * HD_ + 2 * i;
    k0 = qkvf[base]; k1 = qkvf[base + 1];
    v0 = qkvf[base + 1024]; v1 = qkvf[base + 1025];
  }
  long ko = ((long)bh) * (L_ * HD_) + pos * HD_ + 2 * i;
  f16x2 kw; kw.x = (f16)(k0 * c - k1 * s); kw.y = (f16)(k0 * s + k1 * c);
  *(f16x2*)(kh + ko) = kw;
  f16x2 vw; vw.x = (f16)v0; vw.y = (f16)v1;
  *(f16x2*)(vh + ko) = vw;
  if (pos >= M_) {
    long qbase = ((long)(b * M_ + pos - M_)) * 3072 + h * HD_ + 2 * i;
    float q0 = qkvf[qbase], q1 = qkvf[qbase + 1];
    long qo = ((long)bh) * (M_ * HD_) + (pos - M_) * HD_ + 2 * i;
    f16x2 qw; qw.x = (f16)((q0 * c - q1 * s) * 0.125f);
    qw.y = (f16)((q0 * s + q1 * c) * 0.125f);
    *(f16x2*)(qh + qo) = qw;
  }
}

// vhalf [bh][1024][64] -> vhalfT [bh][64][1024]
__global__ __launch_bounds__(256) void transpose_vh(const f16* __restrict__ vin,
                                                    f16* __restrict__ vout) {
  __shared__ f16 tile[64][66];
  int pt = blockIdx.x, bh = blockIdx.y;
  int tid = threadIdx.x;
  int row = tid >> 2, d0 = (tid & 3) * 16;
  const f16* src = vin + ((size_t)bh * 1024 + pt * 64 + row) * 64 + d0;
  uint4 a = *(const uint4*)src;
  uint4 b = *(const uint4*)(src + 8);
  uint* tw = (uint*)&tile[row][d0];   // 4B-aligned (stride 66 f16 = 132B)
  tw[0] = a.x; tw[1] = a.y; tw[2] = a.z; tw[3] = a.w;
  tw[4] = b.x; tw[5] = b.y; tw[6] = b.z; tw[7] = b.w;
  __syncthreads();
  int d = tid >> 2, p0 = (tid & 3) * 16;
  f16 vals[16];
#pragma unroll
  for (int i = 0; i < 16; i++) vals[i] = tile[p0 + i][d];
  f16* dst = vout + ((size_t)bh * 64 + d) * 1024 + pt * 64 + p0;
  *(uint4*)dst = *(uint4*)&vals[0];
  *(uint4*)(dst + 8) = *(uint4*)&vals[8];
}

// ---------------- fp16 MFMA flash attention ----------------
// grid (qt=8, bh=32), 256 thr = 4 waves; wave w owns queries qt*64+w*16+[0..15]
// (attention pos 512+q). Per 64-key chunk: stage K[key][d], V^T[d][key] in
// swizzled LDS; S^T = K@Q^T (C-layout col = query -> per-lane softmax stats);
// fp32 online softmax; P round-trip via per-wave LDS (16x ds_write_b16);
// O += P@V^T. Layouts per m89/m91: A[m=lane&15][k=g*8+j], B[n=lane&15][k=g*8+j],
// C col=lane&15, row=g*4+reg.
__global__ __launch_bounds__(256) void attn_mfma(
    const f16* __restrict__ qh, const f16* __restrict__ kh,
    const f16* __restrict__ vT, bf16* __restrict__ om_bf,
    bf16* __restrict__ outs_bf, int t) {
  __shared__ char smem[24576];  // K 8K | V^T 8K | P 4x2K
  int qt = blockIdx.x, bh = blockIdx.y;
  int tid = threadIdx.x;
  int w = tid >> 6, lane = tid & 63;
  int g = lane >> 4, n16 = lane & 15;
  int numc = 9 + qt;
  int pos = 512 + qt * 64 + w * 16 + n16;  // this lane's query position

  f16x8 qf[2];
  {
    const f16* qp = qh + ((size_t)bh * 512 + qt * 64 + w * 16 + n16) * 64 + g * 8;
    qf[0] = *(const f16x8*)(qp);
    qf[1] = *(const f16x8*)(qp + 32);
  }
  floatx4 O[4] = {};
  float mrun = -1e30f, lrun = 0.f;

  int id0 = tid, id1 = tid + 256;
  int r0 = id0 >> 3, c0 = id0 & 7;
  int r1 = id1 >> 3, c1 = id1 & 7;
  int lof0 = ((r0 << 3) | (c0 ^ (r0 & 7))) * 16;
  int lof1 = ((r1 << 3) | (c1 ^ (r1 & 7))) * 16;
  const f16* kbase = kh + (size_t)bh * (1024 * 64);
  const f16* vbase = vT + (size_t)bh * (64 * 1024);

  uint4 kv0 = *(const uint4*)(kbase + (size_t)r0 * 64 + c0 * 8);
  uint4 kv1 = *(const uint4*)(kbase + (size_t)r1 * 64 + c1 * 8);
  uint4 vv0 = *(const uint4*)(vbase + (size_t)r0 * 1024 + c0 * 8);
  uint4 vv1 = *(const uint4*)(vbase + (size_t)r1 * 1024 + c1 * 8);

  char* Pw = smem + 16384 + w * 2048;

  for (int c = 0; c < numc; ++c) {
    __syncthreads();
    *(uint4*)(smem + lof0) = kv0;
    *(uint4*)(smem + lof1) = kv1;
    *(uint4*)(smem + 8192 + lof0) = vv0;
    *(uint4*)(smem + 8192 + lof1) = vv1;
    if (c + 1 < numc) {
      int kb2 = (c + 1) * 64;
      kv0 = *(const uint4*)(kbase + (size_t)(kb2 + r0) * 64 + c0 * 8);
      kv1 = *(const uint4*)(kbase + (size_t)(kb2 + r1) * 64 + c1 * 8);
      vv0 = *(const uint4*)(vbase + (size_t)r0 * 1024 + kb2 + c0 * 8);
      vv1 = *(const uint4*)(vbase + (size_t)r1 * 1024 + kb2 + c1 * 8);
    }
    __syncthreads();

    // S^T = K @ Q^T  (rows=keys, cols=queries)
    floatx4 S[4] = {};
#pragma unroll
    for (int kk = 0; kk < 2; ++kk) {
#pragma unroll
      for (int tn = 0; tn < 4; ++tn) {
        int row = tn * 16 + n16;
        f16x8 kf = *(const f16x8*)(smem + (((row << 3) | ((kk * 4 + g) ^ (row & 7))) * 16));
        S[tn] = __builtin_amdgcn_mfma_f32_16x16x32_f16(kf, qf[kk], S[tn], 0, 0, 0);
      }
    }
    // causal mask (only the final chunk can violate key<=pos)
    if (c == numc - 1) {
      int kb = c * 64;
#pragma unroll
      for (int tn = 0; tn < 4; ++tn)
#pragma unroll
        for (int r = 0; r < 4; ++r) {
          int key = kb + tn * 16 + g * 4 + r;
          if (key > pos) S[tn][r] = -1e30f;
        }
    }
    // per-lane online softmax (col = this lane's query)
    float smax = -1e30f;
#pragma unroll
    for (int tn = 0; tn < 4; ++tn)
#pragma unroll
      for (int r = 0; r < 4; ++r) smax = fmaxf(smax, S[tn][r]);
    smax = fmaxf(smax, __shfl_xor(smax, 16));
    smax = fmaxf(smax, __shfl_xor(smax, 32));
    float newm = fmaxf(mrun, smax);
    float corr = __expf(mrun - newm);
    mrun = newm;
    float lsum = 0.f;
    f16 pv[16];
#pragma unroll
    for (int tn = 0; tn < 4; ++tn)
#pragma unroll
      for (int r = 0; r < 4; ++r) {
        float p = __expf(S[tn][r] - newm);
        lsum += p;
        pv[tn * 4 + r] = (f16)p;
      }
    lsum += __shfl_xor(lsum, 16);
    lsum += __shfl_xor(lsum, 32);
    lrun = lrun * corr + lsum;
    float cr[4];
#pragma unroll
    for (int r = 0; r < 4; ++r) cr[r] = __shfl(corr, g * 4 + r);
#pragma unroll
    for (int dt = 0; dt < 4; ++dt)
#pragma unroll
      for (int r = 0; r < 4; ++r) O[dt][r] *= cr[r];
    // P (row-major [query][key], swizzled) — per-wave buffer, in-wave DS order
#pragma unroll
    for (int tn = 0; tn < 4; ++tn)
#pragma unroll
      for (int r = 0; r < 4; ++r) {
        int kap = tn * 16 + g * 4 + r;
        *(f16*)(Pw + (((n16 << 3) | ((kap >> 3) ^ (n16 & 7))) * 16 + (kap & 7) * 2)) =
            pv[tn * 4 + r];
      }
    // O += P @ V
#pragma unroll
    for (int kk = 0; kk < 2; ++kk) {
      f16x8 pf = *(const f16x8*)(Pw + (((n16 << 3) | ((kk * 4 + g) ^ (n16 & 7))) * 16));
#pragma unroll
      for (int dt = 0; dt < 4; ++dt) {
        int row = dt * 16 + n16;
        f16x8 vf =
            *(const f16x8*)(smem + 8192 + (((row << 3) | ((kk * 4 + g) ^ (row & 7))) * 16));
        O[dt] = __builtin_amdgcn_mfma_f32_16x16x32_f16(pf, vf, O[dt], 0, 0, 0);
      }
    }
  }
  float rl = 1.0f / lrun;
  float rlr[4];
#pragma unroll
  for (int r = 0; r < 4; ++r) rlr[r] = __shfl(rl, g * 4 + r);
  int b = bh >> 4, h = bh & 15;
#pragma unroll
  for (int dt = 0; dt < 4; ++dt)
#pragma unroll
    for (int r = 0; r < 4; ++r) {
      int qq = qt * 64 + w * 16 + g * 4 + r;
      bf16 v = __float2bfloat16(O[dt][r] * rlr[r]);
      size_t col = h * 64 + dt * 16 + n16;
      om_bf[((size_t)(b * 512 + qq)) * 1024 + col] = v;
      outs_bf[((size_t)(b * 4096 + t * 512 + qq)) * 1024 + col] = v;
    }
}

// ---------------- launch ----------------
extern "C" void kernel_launch(void* const* d_in, const int* in_sizes, int n_in,
                              void* d_out, int out_size, void* d_ws, size_t ws_size,
                              hipStream_t stream) {
  (void)in_sizes; (void)n_in; (void)out_size; (void)ws_size;
  const void* x   = d_in[0];
  const void* fc  = d_in[1];
  const void* fs  = d_in[2];
  const void* wq  = d_in[3];
  const void* wk  = d_in[4];
  const void* wv  = d_in[5];
  const void* wo  = d_in[6];
  const void* wm  = d_in[7];
  const void* wkm = d_in[8];
  const void* wvm = d_in[9];
  const void* w1  = d_in[10];
  const void* w3  = d_in[11];
  const void* w2  = d_in[12];
  const void* fnw = d_in[13];
  const void* mnw = d_in[14];
  const void* om0 = d_in[15];

  char* p = (char*)d_ws;
  auto alloc = [&](size_t bytes) -> char* {
    char* r = p;
    p += (bytes + 255) & ~(size_t)255;
    return r;
  };
  int*   flag    = (int*)alloc(256);
  bf16*  wqkvT   = (bf16*)alloc((size_t)3 * 1048576 * 2);
  bf16*  wmT     = (bf16*)alloc((size_t)1048576 * 2);
  bf16*  wkmvmT  = (bf16*)alloc((size_t)2 * 1048576 * 2);
  bf16*  w13T    = (bf16*)alloc((size_t)2 * 2883584 * 2);
  bf16*  w2T     = (bf16*)alloc((size_t)2883584 * 2);
  bf16*  woT     = (bf16*)alloc((size_t)1048576 * 2);
  bf16*  xb      = (bf16*)alloc((size_t)8388608 * 2);
  float* cosf    = (float*)alloc((size_t)32768 * 4);
  float* sinf    = (float*)alloc((size_t)32768 * 4);
  float* ffnw    = (float*)alloc((size_t)1024 * 4);
  float* memw    = (float*)alloc((size_t)1024 * 4);
  bf16*  om_bf   = (bf16*)alloc((size_t)1048576 * 2);
  bf16*  outs_bf = (bf16*)alloc((size_t)8388608 * 2);
  float* qkvf    = (float*)alloc((size_t)3145728 * 4);
  float* om2a    = (float*)alloc((size_t)1048576 * 4);
  bf16*  h_bf    = (bf16*)alloc((size_t)1048576 * 2);
  float* g13     = (float*)alloc((size_t)5767168 * 4);
  bf16*  u_bf    = (bf16*)alloc((size_t)2883584 * 2);
  float* fbuf    = (float*)alloc((size_t)1048576 * 4);
  bf16*  om2_bf  = (bf16*)alloc((size_t)1048576 * 2);
  float* mkv     = (float*)alloc((size_t)2097152 * 4);
  f16*   qhalf   = (f16*)alloc((size_t)1048576 * 2);
  f16*   khalf   = (f16*)alloc((size_t)2097152 * 2);
  f16*   vhalf   = (f16*)alloc((size_t)2097152 * 2);
  f16*   vhalfT  = (f16*)alloc((size_t)2097152 * 2);

  dim3 tb(256);
  probe_dtype<<<1, 64, 0, stream>>>(x, flag);

  transpose_cast<<<dim3(32, 32), tb, 0, stream>>>(wq, wqkvT, 1024, 1024, flag);
  transpose_cast<<<dim3(32, 32), tb, 0, stream>>>(wk, wqkvT + 1048576, 1024, 1024, flag);
  transpose_cast<<<dim3(32, 32), tb, 0, stream>>>(wv, wqkvT + 2 * 1048576, 1024, 1024, flag);
  transpose_cast<<<dim3(32, 32), tb, 0, stream>>>(wm, wmT, 1024, 1024, flag);
  transpose_cast<<<dim3(32, 32), tb, 0, stream>>>(wkm, wkmvmT, 1024, 1024, flag);
  transpose_cast<<<dim3(32, 32), tb, 0, stream>>>(wvm, wkmvmT + 1048576, 1024, 1024, flag);
  transpose_cast<<<dim3(88, 32), tb, 0, stream>>>(w1, w13T, 1024, 2816, flag);
  transpose_cast<<<dim3(88, 32), tb, 0, stream>>>(w3, w13T + 2883584, 1024, 2816, flag);
  transpose_cast<<<dim3(32, 88), tb, 0, stream>>>(w2, w2T, 2816, 1024, flag);
  transpose_cast<<<dim3(32, 32), tb, 0, stream>>>(wo, woT, 1024, 1024, flag);

  cast_to_bf16<<<32768, tb, 0, stream>>>(x, xb, 8388608, flag);
  cast_to_f32<<<128, tb, 0, stream>>>(fc, cosf, 32768, flag);
  cast_to_f32<<<128, tb, 0, stream>>>(fs, sinf, 32768, flag);
  cast_to_f32<<<4, tb, 0, stream>>>(fnw, ffnw, 1024, flag);
  cast_to_f32<<<4, tb, 0, stream>>>(mnw, memw, 1024, flag);
  init_om<<<4096, tb, 0, stream>>>(om0, om_bf, flag);

  for (int t = 0; t < NSTEP; ++t) {
    gemm_bf16<<<dim3(48, 16), tb, 0, stream>>>(xb, wqkvT, qkvf, nullptr, flag,
                                               1024, 3072, 1024, 512, 4096, t * 512, 0);
    gemm_bf16<<<dim3(16, 16), tb, 0, stream>>>(om_bf, wmT, om2a, nullptr, flag,
                                               1024, 1024, 1024, 1024, 1024, 0, 0);
    rmsnorm_cast<<<1024, tb, 0, stream>>>(om2a, ffnw, h_bf, nullptr);
    gemm_bf16<<<dim3(88, 16), tb, 0, stream>>>(h_bf, w13T, g13, nullptr, flag,
                                               1024, 5632, 1024, 1024, 1024, 0, 0);
    silu_mul_cast<<<dim3(11, 1024), tb, 0, stream>>>(g13, u_bf);
    gemm_bf16<<<dim3(16, 16), tb, 0, stream>>>(u_bf, w2T, fbuf, nullptr, flag,
                                               1024, 1024, 2816, 1024, 1024, 0, 0);
    rmsnorm_cast<<<1024, tb, 0, stream>>>(om2a, memw, om2_bf, fbuf);
    gemm_bf16<<<dim3(32, 16), tb, 0, stream>>>(om2_bf, wkmvmT, mkv, nullptr, flag,
                                               1024, 2048, 1024, 1024, 1024, 0, 0);
    rope_build<<<4096, tb, 0, stream>>>(qkvf, mkv, cosf, sinf, qhalf, khalf, vhalf);
    transpose_vh<<<dim3(16, 32), tb, 0, stream>>>(vhalf, vhalfT);
    attn_mfma<<<dim3(8, 32), tb, 0, stream>>>(qhalf, khalf, vhalfT, om_bf, outs_bf, t);
  }
  gemm_bf16<<<dim3(16, 128), tb, 0, stream>>>(outs_bf, woT, nullptr, d_out, flag,
                                              8192, 1024, 1024, 8192, 8192, 0, 1);
}

// Round 4
// 1270.483 us; speedup vs baseline: 7.7372x; 1.0376x over previous
//
#include <hip/hip_runtime.h>
#include <hip/hip_bf16.h>

// B=2, S=4096, D=1024, H=16, HD=64, M=512, L=1024, HID=2816, 8 scan steps.
// R3 -> R4: (1) hoist qkv GEMM + x-side rope/V-transpose out of the scan loop
// (scan-invariant); (2) 128x128-tile GEMM w/ global_load_lds width=16 (m97
// structure) for the big GEMMs (qkv, w13, final wo); (3) qkv/kmvm GEMMs emit
// fp16 directly. Attention numerics unchanged (fp32 softmax/accum).

#define D_    1024
#define H_    16
#define HD_   64
#define M_    512
#define L_    1024
#define HID_  2816
#define NSTEP 8

typedef __hip_bfloat16 bf16;
typedef _Float16 f16;
typedef __attribute__((ext_vector_type(8))) short short8;
typedef __attribute__((ext_vector_type(8))) _Float16 f16x8;
typedef __attribute__((ext_vector_type(2))) _Float16 f16x2;
typedef __attribute__((ext_vector_type(4))) float floatx4;

// ---------------- dtype probe ----------------
__global__ void probe_dtype(const void* x, int* flag) {
  int lane = threadIdx.x;
  unsigned short v = ((const unsigned short*)x)[2 * lane];
  int e = (v >> 7) & 0xFF;
  bool sane = (e >= 100 && e <= 140);
  unsigned long long m = __ballot(sane);
  if (lane == 0) flag[0] = (__popcll(m) >= 40) ? 1 : 0;  // 1 = bf16 inputs
}

__device__ __forceinline__ float load_any(const void* p, long i, int isbf) {
  return isbf ? __bfloat162float(((const bf16*)p)[i]) : ((const float*)p)[i];
}

// ---------------- converts ----------------
__global__ __launch_bounds__(256) void transpose_cast(const void* in, bf16* out,
                                                      int K, int N, const int* flagp) {
  __shared__ float tile[32][33];
  int isbf = flagp[0];
  int tx = threadIdx.x & 31, ty = threadIdx.x >> 5;
  int n = blockIdx.x * 32 + tx;
#pragma unroll
  for (int i = 0; i < 4; i++) {
    int k = blockIdx.y * 32 + ty + i * 8;
    tile[ty + i * 8][tx] = load_any(in, (long)k * N + n, isbf);
  }
  __syncthreads();
  int k2 = blockIdx.y * 32 + tx;
#pragma unroll
  for (int i = 0; i < 4; i++) {
    int n2 = blockIdx.x * 32 + ty + i * 8;
    out[(long)n2 * K + k2] = __float2bfloat16(tile[tx][ty + i * 8]);
  }
}

__global__ __launch_bounds__(256) void cast_to_bf16(const void* in, bf16* out, int n,
                                                    const int* flagp) {
  int i = blockIdx.x * 256 + threadIdx.x;
  if (i < n) out[i] = __float2bfloat16(load_any(in, i, flagp[0]));
}

__global__ __launch_bounds__(256) void cast_to_f32(const void* in, float* out, int n,
                                                   const int* flagp) {
  int i = blockIdx.x * 256 + threadIdx.x;
  if (i < n) out[i] = load_any(in, i, flagp[0]);
}

__global__ __launch_bounds__(256) void init_om(const void* in, bf16* om, const int* flagp) {
  int i = blockIdx.x * 256 + threadIdx.x;  // 1048576
  int rem = i & (M_ * D_ - 1);
  om[i] = __float2bfloat16(load_any(in, rem, flagp[0]));
}

// ---------------- 64x64 MFMA GEMM (small-M shapes) ----------------
// out_mode: 0 = f32, 1 = f16, 2 = d_out per flag
__global__ __launch_bounds__(256) void gemm64(
    const bf16* __restrict__ A, const bf16* __restrict__ WT,
    void* __restrict__ out, const int* __restrict__ flagp,
    int N, int K, int out_mode) {
  __shared__ char smem[16384];
  char* aT = smem;
  char* bT = smem + 8192;
  int tid = threadIdx.x;
  int C0 = blockIdx.x * 64, R0 = blockIdx.y * 64;
  int wave = tid >> 6, lane = tid & 63;
  int wm_ = wave >> 1, wn_ = wave & 1;
  floatx4 acc[2][2] = {};

  int q0 = tid, q1 = tid + 256;
  int am0 = q0 >> 3, ac0 = q0 & 7;
  int am1 = q1 >> 3, ac1 = q1 & 7;
  long grow0 = R0 + am0, grow1 = R0 + am1;
  long bn0 = (long)(C0 + am0) * K, bn1 = (long)(C0 + am1) * K;
  int lofa0 = (am0 * 8 + (ac0 ^ (am0 & 7))) * 16;
  int lofa1 = (am1 * 8 + (ac1 ^ (am1 & 7))) * 16;

  for (int k0 = 0; k0 < K; k0 += 64) {
    uint4 va0 = *(const uint4*)(A + grow0 * K + k0 + ac0 * 8);
    uint4 va1 = *(const uint4*)(A + grow1 * K + k0 + ac1 * 8);
    uint4 vb0 = *(const uint4*)(WT + bn0 + k0 + ac0 * 8);
    uint4 vb1 = *(const uint4*)(WT + bn1 + k0 + ac1 * 8);
    __syncthreads();
    *(uint4*)(aT + lofa0) = va0;
    *(uint4*)(aT + lofa1) = va1;
    *(uint4*)(bT + lofa0) = vb0;
    *(uint4*)(bT + lofa1) = vb1;
    __syncthreads();
#pragma unroll
    for (int kki = 0; kki < 2; ++kki) {
      int cbase = kki * 4 + (lane >> 4);
      short8 af[2], bfr[2];
#pragma unroll
      for (int i = 0; i < 2; ++i) {
        int ml = wm_ * 32 + i * 16 + (lane & 15);
        af[i] = *(const short8*)(aT + (ml * 8 + (cbase ^ (ml & 7))) * 16);
        int nl = wn_ * 32 + i * 16 + (lane & 15);
        bfr[i] = *(const short8*)(bT + (nl * 8 + (cbase ^ (nl & 7))) * 16);
      }
#pragma unroll
      for (int i = 0; i < 2; ++i)
#pragma unroll
        for (int j = 0; j < 2; ++j)
          acc[i][j] = __builtin_amdgcn_mfma_f32_16x16x32_bf16(af[i], bfr[j], acc[i][j], 0, 0, 0);
    }
  }
  int isbf = flagp[0];
#pragma unroll
  for (int i = 0; i < 2; ++i)
#pragma unroll
    for (int j = 0; j < 2; ++j) {
      int row = R0 + wm_ * 32 + i * 16 + (lane >> 4) * 4;
      int col = C0 + wn_ * 32 + j * 16 + (lane & 15);
#pragma unroll
      for (int rg = 0; rg < 4; ++rg) {
        float v = acc[i][j][rg];
        long off = (long)(row + rg) * N + col;
        if (out_mode == 0) ((float*)out)[off] = v;
        else if (out_mode == 1) ((f16*)out)[off] = (f16)v;
        else {
          if (isbf) ((bf16*)out)[off] = __float2bfloat16(v);
          else ((float*)out)[off] = v;
        }
      }
    }
}

// ---------------- 128x128 MFMA GEMM, global_load_lds (m97 structure) --------
// Swizzle on the GLOBAL side: lane covering LDS physical chunk p of row m loads
// global chunk p ^ (m&7); ds_read of logical chunk cb hits (m*8 + (cb^(m&7)))*16.
__global__ __launch_bounds__(256) void gemm128(
    const bf16* __restrict__ A, const bf16* __restrict__ WT,
    void* __restrict__ out, const int* __restrict__ flagp,
    int N, int K, int out_mode) {
  __shared__ char smem[32768];  // A 16K | B 16K
  int tid = threadIdx.x;
  int w = tid >> 6, lane = tid & 63;
  int C0 = blockIdx.x * 128, R0 = blockIdx.y * 128;
  int wm = (w >> 1) * 64, wn = (w & 1) * 64;
  int g = lane >> 4, n16 = lane & 15;
  floatx4 acc[4][4] = {};
  int lr = lane >> 3, lc = lane & 7;

  for (int k0 = 0; k0 < K; k0 += 64) {
    __syncthreads();
#pragma unroll
    for (int i = 0; i < 4; ++i) {
      int m = w * 32 + i * 8 + lr;
      int cg = lc ^ (m & 7);
      const bf16* ga = A + (size_t)(R0 + m) * K + k0 + cg * 8;
      const bf16* gb = WT + (size_t)(C0 + m) * K + k0 + cg * 8;
      __builtin_amdgcn_global_load_lds(
          (const __attribute__((address_space(1))) void*)ga,
          (__attribute__((address_space(3))) void*)(smem + (w * 32 + i * 8) * 128),
          16, 0, 0);
      __builtin_amdgcn_global_load_lds(
          (const __attribute__((address_space(1))) void*)gb,
          (__attribute__((address_space(3))) void*)(smem + 16384 + (w * 32 + i * 8) * 128),
          16, 0, 0);
    }
    __syncthreads();
#pragma unroll
    for (int kk = 0; kk < 2; ++kk) {
      short8 af[4], bfr[4];
#pragma unroll
      for (int i = 0; i < 4; ++i) {
        int ml = wm + i * 16 + n16;
        af[i] = *(const short8*)(smem + (ml * 8 + ((kk * 4 + g) ^ (ml & 7))) * 16);
        int nl = wn + i * 16 + n16;
        bfr[i] = *(const short8*)(smem + 16384 + (nl * 8 + ((kk * 4 + g) ^ (nl & 7))) * 16);
      }
#pragma unroll
      for (int i = 0; i < 4; ++i)
#pragma unroll
        for (int j = 0; j < 4; ++j)
          acc[i][j] = __builtin_amdgcn_mfma_f32_16x16x32_bf16(af[i], bfr[j], acc[i][j], 0, 0, 0);
    }
  }
  int isbf = flagp[0];
#pragma unroll
  for (int i = 0; i < 4; ++i)
#pragma unroll
    for (int j = 0; j < 4; ++j) {
      int row = R0 + wm + i * 16 + g * 4;
      int col = C0 + wn + j * 16 + n16;
#pragma unroll
      for (int rg = 0; rg < 4; ++rg) {
        float v = acc[i][j][rg];
        long off = (long)(row + rg) * N + col;
        if (out_mode == 0) ((float*)out)[off] = v;
        else if (out_mode == 1) ((f16*)out)[off] = (f16)v;
        else {
          if (isbf) ((bf16*)out)[off] = __float2bfloat16(v);
          else ((float*)out)[off] = v;
        }
      }
    }
}

// ---------------- elementwise ----------------
__global__ __launch_bounds__(256) void rmsnorm_cast(const float* __restrict__ X,
                                                    const float* __restrict__ Wn,
                                                    bf16* __restrict__ Y,
                                                    const float* __restrict__ Xadd) {
  int row = blockIdx.x, tid = threadIdx.x;
  const float* xr = X + (long)row * D_;
  float vals[4], ss = 0.f;
#pragma unroll
  for (int i = 0; i < 4; i++) {
    int c = tid + i * 256;
    float v = xr[c];
    if (Xadd) v += Xadd[(long)row * D_ + c];
    vals[i] = v;
    ss += v * v;
  }
#pragma unroll
  for (int off = 32; off; off >>= 1) ss += __shfl_xor(ss, off);
  __shared__ float wsum[4];
  int wv = tid >> 6, lane = tid & 63;
  if (lane == 0) wsum[wv] = ss;
  __syncthreads();
  ss = wsum[0] + wsum[1] + wsum[2] + wsum[3];
  float r = rsqrtf(ss * (1.0f / D_) + 1e-5f);
#pragma unroll
  for (int i = 0; i < 4; i++) {
    int c = tid + i * 256;
    Y[(long)row * D_ + c] = __float2bfloat16(vals[i] * r * Wn[c]);
  }
}

__global__ __launch_bounds__(256) void silu_mul_cast(const float* __restrict__ g13,
                                                     bf16* __restrict__ u) {
  int c = blockIdx.x * 256 + threadIdx.x;  // 0..2815
  int r = blockIdx.y;
  float a = g13[(long)r * (2 * HID_) + c];
  float b = g13[(long)r * (2 * HID_) + HID_ + c];
  float s = a / (1.f + __expf(-a));
  u[(long)r * HID_ + c] = __float2bfloat16(s * b);
}

// ---------------- rope (x side, all 8 slabs, upfront) ----------------
// qkv: [8192 rows = b*4096+t*512+m][3072] f16. Outputs per slab (t*32+bh):
// q_x/k_x [slab][512][64], v_xT [slab][64][512].
__global__ __launch_bounds__(256) void rope_x(
    const f16* __restrict__ qkv, const float* __restrict__ cosf,
    const float* __restrict__ sinf, f16* __restrict__ q_x,
    f16* __restrict__ k_x, f16* __restrict__ v_xT) {
  __shared__ f16 tile[64][72];
  int pt = blockIdx.x;  // pos tile 0..7
  int t = blockIdx.y;   // 0..7
  int bh = blockIdx.z;  // 0..31
  int b = bh >> 4, h = bh & 15;
  int tid = threadIdx.x;
  int i = tid & 31, p0 = tid >> 5;
  size_t slab = (size_t)t * 32 + bh;
#pragma unroll
  for (int j = 0; j < 8; ++j) {
    int pl = p0 + j * 8;
    int m = pt * 64 + pl;
    int pos = 512 + m;
    long base = ((long)b * 4096 + t * 512 + m) * 3072 + h * 64 + 2 * i;
    float c = cosf[pos * 32 + i], s = sinf[pos * 32 + i];
    float q0 = (float)qkv[base], q1 = (float)qkv[base + 1];
    f16x2 qw; qw.x = (f16)((q0 * c - q1 * s) * 0.125f);
    qw.y = (f16)((q0 * s + q1 * c) * 0.125f);
    *(f16x2*)(q_x + (slab * 512 + m) * 64 + 2 * i) = qw;
    float k0 = (float)qkv[base + 1024], k1 = (float)qkv[base + 1025];
    f16x2 kw; kw.x = (f16)(k0 * c - k1 * s); kw.y = (f16)(k0 * s + k1 * c);
    *(f16x2*)(k_x + (slab * 512 + m) * 64 + 2 * i) = kw;
    tile[2 * i][pl] = qkv[base + 2048];
    tile[2 * i + 1][pl] = qkv[base + 2049];
  }
  __syncthreads();
#pragma unroll
  for (int j = 0; j < 8; ++j) {
    int d = p0 + j * 8;
    f16x2 vv; vv.x = tile[d][2 * i]; vv.y = tile[d][2 * i + 1];
    *(f16x2*)(v_xT + (slab * 64 + d) * 512 + pt * 64 + 2 * i) = vv;
  }
}

// ---------------- rope (memory side, per step) ----------------
// mkv: [1024 rows = b*512+m][2048] f16 (mk | mv). pos = m (0..511).
__global__ __launch_bounds__(256) void rope_mem(
    const f16* __restrict__ mkv, const float* __restrict__ cosf,
    const float* __restrict__ sinf, f16* __restrict__ k_mem,
    f16* __restrict__ v_memT) {
  __shared__ f16 tile[64][72];
  int pt = blockIdx.x;  // 0..7
  int bh = blockIdx.y;  // 0..31
  int b = bh >> 4, h = bh & 15;
  int tid = threadIdx.x;
  int i = tid & 31, p0 = tid >> 5;
#pragma unroll
  for (int j = 0; j < 8; ++j) {
    int pl = p0 + j * 8;
    int pos = pt * 64 + pl;
    long base = ((long)(b * 512 + pos)) * 2048 + h * 64 + 2 * i;
    float c = cosf[pos * 32 + i], s = sinf[pos * 32 + i];
    float k0 = (float)mkv[base], k1 = (float)mkv[base + 1];
    f16x2 kw; kw.x = (f16)(k0 * c - k1 * s); kw.y = (f16)(k0 * s + k1 * c);
    *(f16x2*)(k_mem + ((size_t)bh * 512 + pos) * 64 + 2 * i) = kw;
    tile[2 * i][pl] = mkv[base + 1024];
    tile[2 * i + 1][pl] = mkv[base + 1025];
  }
  __syncthreads();
#pragma unroll
  for (int j = 0; j < 8; ++j) {
    int d = p0 + j * 8;
    f16x2 vv; vv.x = tile[d][2 * i]; vv.y = tile[d][2 * i + 1];
    *(f16x2*)(v_memT + ((size_t)bh * 64 + d) * 512 + pt * 64 + 2 * i) = vv;
  }
}

// ---------------- fp16 MFMA flash attention ----------------
// Keys: chunks 0..7 = memory (k_mem/v_memT), chunks 8.. = x slab t (k_x/v_xT).
__global__ __launch_bounds__(256) void attn_mfma(
    const f16* __restrict__ q_x, const f16* __restrict__ k_mem,
    const f16* __restrict__ v_memT, const f16* __restrict__ k_x,
    const f16* __restrict__ v_xT, bf16* __restrict__ om_bf,
    bf16* __restrict__ outs_bf, int t) {
  __shared__ char smem[24576];  // K 8K | V^T 8K | P 4x2K
  int qt = blockIdx.x, bh = blockIdx.y;
  int tid = threadIdx.x;
  int w = tid >> 6, lane = tid & 63;
  int g = lane >> 4, n16 = lane & 15;
  int numc = 9 + qt;
  int pos = 512 + qt * 64 + w * 16 + n16;
  size_t slab = (size_t)t * 32 + bh;

  f16x8 qf[2];
  {
    const f16* qp = q_x + (slab * 512 + qt * 64 + w * 16 + n16) * 64 + g * 8;
    qf[0] = *(const f16x8*)(qp);
    qf[1] = *(const f16x8*)(qp + 32);
  }
  floatx4 O[4] = {};
  float mrun = -1e30f, lrun = 0.f;

  int id0 = tid, id1 = tid + 256;
  int r0 = id0 >> 3, c0 = id0 & 7;
  int r1 = id1 >> 3, c1 = id1 & 7;
  int lof0 = ((r0 << 3) | (c0 ^ (r0 & 7))) * 16;
  int lof1 = ((r1 << 3) | (c1 ^ (r1 & 7))) * 16;

  auto kaddr = [&](int c, int r) -> const f16* {
    return (c < 8) ? k_mem + ((size_t)bh * 512 + c * 64 + r) * 64
                   : k_x + (slab * 512 + (c - 8) * 64 + r) * 64;
  };
  auto vaddr = [&](int c, int d) -> const f16* {
    return (c < 8) ? v_memT + ((size_t)bh * 64 + d) * 512 + c * 64
                   : v_xT + (slab * 64 + d) * 512 + (c - 8) * 64;
  };

  uint4 kv0 = *(const uint4*)(kaddr(0, r0) + c0 * 8);
  uint4 kv1 = *(const uint4*)(kaddr(0, r1) + c1 * 8);
  uint4 vv0 = *(const uint4*)(vaddr(0, r0) + c0 * 8);
  uint4 vv1 = *(const uint4*)(vaddr(0, r1) + c1 * 8);

  char* Pw = smem + 16384 + w * 2048;

  for (int c = 0; c < numc; ++c) {
    __syncthreads();
    *(uint4*)(smem + lof0) = kv0;
    *(uint4*)(smem + lof1) = kv1;
    *(uint4*)(smem + 8192 + lof0) = vv0;
    *(uint4*)(smem + 8192 + lof1) = vv1;
    if (c + 1 < numc) {
      kv0 = *(const uint4*)(kaddr(c + 1, r0) + c0 * 8);
      kv1 = *(const uint4*)(kaddr(c + 1, r1) + c1 * 8);
      vv0 = *(const uint4*)(vaddr(c + 1, r0) + c0 * 8);
      vv1 = *(const uint4*)(vaddr(c + 1, r1) + c1 * 8);
    }
    __syncthreads();

    // S^T = K @ Q^T
    floatx4 S[4] = {};
#pragma unroll
    for (int kk = 0; kk < 2; ++kk) {
#pragma unroll
      for (int tn = 0; tn < 4; ++tn) {
        int row = tn * 16 + n16;
        f16x8 kf = *(const f16x8*)(smem + (((row << 3) | ((kk * 4 + g) ^ (row & 7))) * 16));
        S[tn] = __builtin_amdgcn_mfma_f32_16x16x32_f16(kf, qf[kk], S[tn], 0, 0, 0);
      }
    }
    if (c == numc - 1) {
      int kb = 512 + (c - 8) * 64;  // last chunk is always an x chunk
#pragma unroll
      for (int tn = 0; tn < 4; ++tn)
#pragma unroll
        for (int r = 0; r < 4; ++r) {
          int key = kb + tn * 16 + g * 4 + r;
          if (key > pos) S[tn][r] = -1e30f;
        }
    }
    float smax = -1e30f;
#pragma unroll
    for (int tn = 0; tn < 4; ++tn)
#pragma unroll
      for (int r = 0; r < 4; ++r) smax = fmaxf(smax, S[tn][r]);
    smax = fmaxf(smax, __shfl_xor(smax, 16));
    smax = fmaxf(smax, __shfl_xor(smax, 32));
    float newm = fmaxf(mrun, smax);
    float corr = __expf(mrun - newm);
    mrun = newm;
    float lsum = 0.f;
    f16 pv[16];
#pragma unroll
    for (int tn = 0; tn < 4; ++tn)
#pragma unroll
      for (int r = 0; r < 4; ++r) {
        float p = __expf(S[tn][r] - newm);
        lsum += p;
        pv[tn * 4 + r] = (f16)p;
      }
    lsum += __shfl_xor(lsum, 16);
    lsum += __shfl_xor(lsum, 32);
    lrun = lrun * corr + lsum;
    float cr[4];
#pragma unroll
    for (int r = 0; r < 4; ++r) cr[r] = __shfl(corr, g * 4 + r);
#pragma unroll
    for (int dt = 0; dt < 4; ++dt)
#pragma unroll
      for (int r = 0; r < 4; ++r) O[dt][r] *= cr[r];
#pragma unroll
    for (int tn = 0; tn < 4; ++tn)
#pragma unroll
      for (int r = 0; r < 4; ++r) {
        int kap = tn * 16 + g * 4 + r;
        *(f16*)(Pw + (((n16 << 3) | ((kap >> 3) ^ (n16 & 7))) * 16 + (kap & 7) * 2)) =
            pv[tn * 4 + r];
      }
#pragma unroll
    for (int kk = 0; kk < 2; ++kk) {
      f16x8 pf = *(const f16x8*)(Pw + (((n16 << 3) | ((kk * 4 + g) ^ (n16 & 7))) * 16));
#pragma unroll
      for (int dt = 0; dt < 4; ++dt) {
        int row = dt * 16 + n16;
        f16x8 vf =
            *(const f16x8*)(smem + 8192 + (((row << 3) | ((kk * 4 + g) ^ (row & 7))) * 16));
        O[dt] = __builtin_amdgcn_mfma_f32_16x16x32_f16(pf, vf, O[dt], 0, 0, 0);
      }
    }
  }
  float rl = 1.0f / lrun;
  float rlr[4];
#pragma unroll
  for (int r = 0; r < 4; ++r) rlr[r] = __shfl(rl, g * 4 + r);
  int b = bh >> 4, h = bh & 15;
#pragma unroll
  for (int dt = 0; dt < 4; ++dt)
#pragma unroll
    for (int r = 0; r < 4; ++r) {
      int qq = qt * 64 + w * 16 + g * 4 + r;
      bf16 v = __float2bfloat16(O[dt][r] * rlr[r]);
      size_t col = h * 64 + dt * 16 + n16;
      om_bf[((size_t)(b * 512 + qq)) * 1024 + col] = v;
      outs_bf[((size_t)(b * 4096 + t * 512 + qq)) * 1024 + col] = v;
    }
}

// ---------------- launch ----------------
extern "C" void kernel_launch(void* const* d_in, const int* in_sizes, int n_in,
                              void* d_out, int out_size, void* d_ws, size_t ws_size,
                              hipStream_t stream) {
  (void)in_sizes; (void)n_in; (void)out_size; (void)ws_size;
  const void* x   = d_in[0];
  const void* fc  = d_in[1];
  const void* fs  = d_in[2];
  const void* wq  = d_in[3];
  const void* wk  = d_in[4];
  const void* wv  = d_in[5];
  const void* wo  = d_in[6];
  const void* wm  = d_in[7];
  const void* wkm = d_in[8];
  const void* wvm = d_in[9];
  const void* w1  = d_in[10];
  const void* w3  = d_in[11];
  const void* w2  = d_in[12];
  const void* fnw = d_in[13];
  const void* mnw = d_in[14];
  const void* om0 = d_in[15];

  char* p = (char*)d_ws;
  auto alloc = [&](size_t bytes) -> char* {
    char* r = p;
    p += (bytes + 255) & ~(size_t)255;
    return r;
  };
  int*   flag    = (int*)alloc(256);
  bf16*  wqkvT   = (bf16*)alloc((size_t)3 * 1048576 * 2);
  bf16*  wmT     = (bf16*)alloc((size_t)1048576 * 2);
  bf16*  wkmvmT  = (bf16*)alloc((size_t)2 * 1048576 * 2);
  bf16*  w13T    = (bf16*)alloc((size_t)2 * 2883584 * 2);
  bf16*  w2T     = (bf16*)alloc((size_t)2883584 * 2);
  bf16*  woT     = (bf16*)alloc((size_t)1048576 * 2);
  bf16*  xb      = (bf16*)alloc((size_t)8388608 * 2);
  float* cosf    = (float*)alloc((size_t)32768 * 4);
  float* sinf    = (float*)alloc((size_t)32768 * 4);
  float* ffnw    = (float*)alloc((size_t)1024 * 4);
  float* memw    = (float*)alloc((size_t)1024 * 4);
  bf16*  om_bf   = (bf16*)alloc((size_t)1048576 * 2);
  bf16*  outs_bf = (bf16*)alloc((size_t)8388608 * 2);
  f16*   q_x     = (f16*)alloc((size_t)8 * 32 * 512 * 64 * 2);
  f16*   k_x     = (f16*)alloc((size_t)8 * 32 * 512 * 64 * 2);
  f16*   v_xT    = (f16*)alloc((size_t)8 * 32 * 512 * 64 * 2);
  // shared region: qkvf_all (upfront, 50.3 MB) overlaps loop scratch (~49 MB)
  char*  shr     = alloc((size_t)8192 * 3072 * 2);
  f16*   qkvf_all = (f16*)shr;
  char*  lp = shr;
  auto lalloc = [&](size_t bytes) -> char* {
    char* r = lp;
    lp += (bytes + 255) & ~(size_t)255;
    return r;
  };
  float* om2a   = (float*)lalloc((size_t)1048576 * 4);
  bf16*  h_bf   = (bf16*)lalloc((size_t)1048576 * 2);
  float* g13    = (float*)lalloc((size_t)5767168 * 4);
  bf16*  u_bf   = (bf16*)lalloc((size_t)2883584 * 2);
  float* fbuf   = (float*)lalloc((size_t)1048576 * 4);
  bf16*  om2_bf = (bf16*)lalloc((size_t)1048576 * 2);
  f16*   mkv    = (f16*)lalloc((size_t)2097152 * 2);
  f16*   k_mem  = (f16*)lalloc((size_t)1048576 * 2);
  f16*   v_memT = (f16*)lalloc((size_t)1048576 * 2);

  dim3 tb(256);
  probe_dtype<<<1, 64, 0, stream>>>(x, flag);

  transpose_cast<<<dim3(32, 32), tb, 0, stream>>>(wq, wqkvT, 1024, 1024, flag);
  transpose_cast<<<dim3(32, 32), tb, 0, stream>>>(wk, wqkvT + 1048576, 1024, 1024, flag);
  transpose_cast<<<dim3(32, 32), tb, 0, stream>>>(wv, wqkvT + 2 * 1048576, 1024, 1024, flag);
  transpose_cast<<<dim3(32, 32), tb, 0, stream>>>(wm, wmT, 1024, 1024, flag);
  transpose_cast<<<dim3(32, 32), tb, 0, stream>>>(wkm, wkmvmT, 1024, 1024, flag);
  transpose_cast<<<dim3(32, 32), tb, 0, stream>>>(wvm, wkmvmT + 1048576, 1024, 1024, flag);
  transpose_cast<<<dim3(88, 32), tb, 0, stream>>>(w1, w13T, 1024, 2816, flag);
  transpose_cast<<<dim3(88, 32), tb, 0, stream>>>(w3, w13T + 2883584, 1024, 2816, flag);
  transpose_cast<<<dim3(32, 88), tb, 0, stream>>>(w2, w2T, 2816, 1024, flag);
  transpose_cast<<<dim3(32, 32), tb, 0, stream>>>(wo, woT, 1024, 1024, flag);

  cast_to_bf16<<<32768, tb, 0, stream>>>(x, xb, 8388608, flag);
  cast_to_f32<<<128, tb, 0, stream>>>(fc, cosf, 32768, flag);
  cast_to_f32<<<128, tb, 0, stream>>>(fs, sinf, 32768, flag);
  cast_to_f32<<<4, tb, 0, stream>>>(fnw, ffnw, 1024, flag);
  cast_to_f32<<<4, tb, 0, stream>>>(mnw, memw, 1024, flag);
  init_om<<<4096, tb, 0, stream>>>(om0, om_bf, flag);

  // hoisted: qkv for all 8 steps (8192x3072x1024), then x-side rope/transpose
  gemm128<<<dim3(24, 64), tb, 0, stream>>>(xb, wqkvT, qkvf_all, flag, 3072, 1024, 1);
  rope_x<<<dim3(8, 8, 32), tb, 0, stream>>>(qkvf_all, cosf, sinf, q_x, k_x, v_xT);

  for (int t = 0; t < NSTEP; ++t) {
    gemm64<<<dim3(16, 16), tb, 0, stream>>>(om_bf, wmT, om2a, flag, 1024, 1024, 0);
    rmsnorm_cast<<<1024, tb, 0, stream>>>(om2a, ffnw, h_bf, nullptr);
    gemm128<<<dim3(44, 8), tb, 0, stream>>>(h_bf, w13T, g13, flag, 5632, 1024, 0);
    silu_mul_cast<<<dim3(11, 1024), tb, 0, stream>>>(g13, u_bf);
    gemm64<<<dim3(16, 16), tb, 0, stream>>>(u_bf, w2T, fbuf, flag, 1024, 2816, 0);
    rmsnorm_cast<<<1024, tb, 0, stream>>>(om2a, memw, om2_bf, fbuf);
    gemm64<<<dim3(32, 16), tb, 0, stream>>>(om2_bf, wkmvmT, mkv, flag, 2048, 1024, 1);
    rope_mem<<<dim3(8, 32), tb, 0, stream>>>(mkv, cosf, sinf, k_mem, v_memT);
    attn_mfma<<<dim3(8, 32), tb, 0, stream>>>(q_x, k_mem, v_memT, k_x, v_xT,
                                              om_bf, outs_bf, t);
  }
  gemm128<<<dim3(8, 64), tb, 0, stream>>>(outs_bf, woT, d_out, flag, 1024, 1024, 2);
}